// Round 1
// baseline (848.098 us; speedup 1.0000x reference)
//
#include <hip/hip_runtime.h>

#define DF 128

// ---------------- CSR build ----------------
__global__ void hist_kernel(const int* __restrict__ dst, int* __restrict__ cnt, int E) {
    int e = blockIdx.x * blockDim.x + threadIdx.x;
    if (e < E) atomicAdd(&cnt[dst[e]], 1);
}

// per-block (1024-elem chunk) sums
__global__ void scan1_kernel(const int* __restrict__ cnt, int* __restrict__ partials, int N) {
    __shared__ int sdata[256];
    int t = threadIdx.x;
    int base = blockIdx.x * 1024 + t * 4;
    int s = 0;
#pragma unroll
    for (int j = 0; j < 4; ++j) { int i = base + j; if (i < N) s += cnt[i]; }
    sdata[t] = s; __syncthreads();
    for (int off = 128; off > 0; off >>= 1) {
        if (t < off) sdata[t] += sdata[t + off];
        __syncthreads();
    }
    if (t == 0) partials[blockIdx.x] = sdata[0];
}

// exclusive scan of partials (NB <= 256), single block of 256
__global__ void scan2_kernel(int* partials, int NB) {
    __shared__ int sdata[256];
    int t = threadIdx.x;
    int v = (t < NB) ? partials[t] : 0;
    sdata[t] = v; __syncthreads();
    for (int off = 1; off < 256; off <<= 1) {
        int u = (t >= off) ? sdata[t - off] : 0;
        __syncthreads();
        sdata[t] += u;
        __syncthreads();
    }
    partials[t] = sdata[t] - v;  // exclusive
}

// final scan: rowptr + cursor
__global__ void scan3_kernel(const int* __restrict__ cnt, const int* __restrict__ partials,
                             int* __restrict__ rowptr, int* __restrict__ cursor, int N, int E) {
    __shared__ int sdata[256];
    int t = threadIdx.x;
    int base = blockIdx.x * 1024 + t * 4;
    int v[4]; int s = 0;
#pragma unroll
    for (int j = 0; j < 4; ++j) { int i = base + j; v[j] = (i < N) ? cnt[i] : 0; s += v[j]; }
    sdata[t] = s; __syncthreads();
    for (int off = 1; off < 256; off <<= 1) {
        int u = (t >= off) ? sdata[t - off] : 0;
        __syncthreads();
        sdata[t] += u;
        __syncthreads();
    }
    int run = partials[blockIdx.x] + sdata[t] - s;  // exclusive offset for this thread
#pragma unroll
    for (int j = 0; j < 4; ++j) {
        int i = base + j;
        if (i < N) { rowptr[i] = run; cursor[i] = run; run += v[j]; }
    }
    if (blockIdx.x == 0 && t == 0) rowptr[N] = E;
}

__global__ void scatter_kernel(const int* __restrict__ src, const int* __restrict__ dst,
                               int* __restrict__ cursor, int* __restrict__ edge_src, int E) {
    int e = blockIdx.x * blockDim.x + threadIdx.x;
    if (e < E) {
        int d = dst[e];
        int pos = atomicAdd(&cursor[d], 1);
        edge_src[pos] = src[e];
    }
}

// ---------------- mean aggregation: one wave per node ----------------
__global__ __launch_bounds__(256) void aggregate_kernel(
    const float* __restrict__ X, const int* __restrict__ rowptr,
    const int* __restrict__ edge_src, float* __restrict__ out, int N) {
    int node = (int)((blockIdx.x * (unsigned)blockDim.x + threadIdx.x) >> 6);
    int lane = threadIdx.x & 63;
    if (node >= N) return;
    int beg = rowptr[node], end = rowptr[node + 1];
    float2 acc = make_float2(0.f, 0.f);
    int e = beg;
    for (; e + 4 <= end; e += 4) {
        int s0 = edge_src[e + 0], s1 = edge_src[e + 1];
        int s2 = edge_src[e + 2], s3 = edge_src[e + 3];
        float2 v0 = *(const float2*)(X + (size_t)s0 * DF + lane * 2);
        float2 v1 = *(const float2*)(X + (size_t)s1 * DF + lane * 2);
        float2 v2 = *(const float2*)(X + (size_t)s2 * DF + lane * 2);
        float2 v3 = *(const float2*)(X + (size_t)s3 * DF + lane * 2);
        acc.x += v0.x + v1.x + v2.x + v3.x;
        acc.y += v0.y + v1.y + v2.y + v3.y;
    }
    for (; e < end; ++e) {
        int s = edge_src[e];
        float2 v = *(const float2*)(X + (size_t)s * DF + lane * 2);
        acc.x += v.x; acc.y += v.y;
    }
    float inv = 1.0f / fmaxf((float)(end - beg), 1.0f);
    *(float2*)(out + (size_t)node * DF + lane * 2) = make_float2(acc.x * inv, acc.y * inv);
}

// ---------------- fused SAGE GEMM: out = relu(X@Ws + Hn@Wn + b) ----------------
// X may alias out (in-place): each block reads only its own output rows,
// and all reads complete before the epilogue writes. No __restrict__ on X/out.
__global__ __launch_bounds__(256) void sage_gemm_kernel(
    const float* X, const float* Hn,
    const float* __restrict__ Ws, const float* __restrict__ Wn,
    const float* __restrict__ bias, float* out, int M) {
    __shared__ __align__(16) float sX[32][64];   // [k][row] transposed
    __shared__ __align__(16) float sH[32][64];
    __shared__ __align__(16) float sWs[32][128]; // [k][col]
    __shared__ __align__(16) float sWn[32][128];

    const int tid = threadIdx.x;
    const int tx = tid & 31;        // col group -> c0 = tx*4
    const int ty = tid >> 5;        // row group -> r0 = ty*8
    const int c0 = tx * 4;
    const int r0 = ty * 8;
    const int row0 = blockIdx.x * 64;

    float acc[8][4];
#pragma unroll
    for (int r = 0; r < 8; ++r)
#pragma unroll
        for (int c = 0; c < 4; ++c) acc[r][c] = 0.f;

    const int rl = tid >> 2;   // 0..63 : row this thread stages
    const int fq = tid & 3;    // quad within 32-float k-slice
    int grow = row0 + rl; if (grow >= M) grow = M - 1;

    float* sWsf = &sWs[0][0];
    float* sWnf = &sWn[0][0];

    for (int kt = 0; kt < 4; ++kt) {
        // stage W tiles (32x128 each), linear, coalesced
#pragma unroll
        for (int i = 0; i < 4; ++i) {
            int idx = tid * 4 + i * 1024;
            *(float4*)(sWsf + idx) = *(const float4*)&Ws[kt * 32 * 128 + idx];
            *(float4*)(sWnf + idx) = *(const float4*)&Wn[kt * 32 * 128 + idx];
        }
        // stage X,H transposed: this thread loads 2 float4 along k for row rl
#pragma unroll
        for (int h = 0; h < 2; ++h) {
            int q = fq + 4 * h;   // 0..7
            float4 xv = *(const float4*)&X[(size_t)grow * DF + kt * 32 + q * 4];
            sX[q * 4 + 0][rl] = xv.x;
            sX[q * 4 + 1][rl] = xv.y;
            sX[q * 4 + 2][rl] = xv.z;
            sX[q * 4 + 3][rl] = xv.w;
            float4 hv = *(const float4*)&Hn[(size_t)grow * DF + kt * 32 + q * 4];
            sH[q * 4 + 0][rl] = hv.x;
            sH[q * 4 + 1][rl] = hv.y;
            sH[q * 4 + 2][rl] = hv.z;
            sH[q * 4 + 3][rl] = hv.w;
        }
        __syncthreads();
#pragma unroll
        for (int k = 0; k < 32; ++k) {
            float4 xa = *(float4*)&sX[k][r0];
            float4 xb = *(float4*)&sX[k][r0 + 4];
            float4 ha = *(float4*)&sH[k][r0];
            float4 hb = *(float4*)&sH[k][r0 + 4];
            float4 ws = *(float4*)&sWs[k][c0];
            float4 wn = *(float4*)&sWn[k][c0];
            float xr[8] = {xa.x, xa.y, xa.z, xa.w, xb.x, xb.y, xb.z, xb.w};
            float hr[8] = {ha.x, ha.y, ha.z, ha.w, hb.x, hb.y, hb.z, hb.w};
            float wsc[4] = {ws.x, ws.y, ws.z, ws.w};
            float wnc[4] = {wn.x, wn.y, wn.z, wn.w};
#pragma unroll
            for (int r = 0; r < 8; ++r)
#pragma unroll
                for (int c = 0; c < 4; ++c)
                    acc[r][c] += xr[r] * wsc[c] + hr[r] * wnc[c];
        }
        __syncthreads();
    }

    float4 bv = *(const float4*)&bias[c0];
#pragma unroll
    for (int r = 0; r < 8; ++r) {
        int go = row0 + r0 + r;
        if (go < M) {
            float4 o;
            o.x = fmaxf(acc[r][0] + bv.x, 0.f);
            o.y = fmaxf(acc[r][1] + bv.y, 0.f);
            o.z = fmaxf(acc[r][2] + bv.z, 0.f);
            o.w = fmaxf(acc[r][3] + bv.w, 0.f);
            *(float4*)&out[(size_t)go * DF + c0] = o;
        }
    }
}

extern "C" void kernel_launch(void* const* d_in, const int* in_sizes, int n_in,
                              void* d_out, int out_size, void* d_ws, size_t ws_size,
                              hipStream_t stream) {
    const int N = in_sizes[0] / DF;   // 100000
    const int E = in_sizes[1];        // 1600000

    const float* x   = (const float*)d_in[0];
    const int*   src = (const int*)d_in[1];
    const int*   dst = (const int*)d_in[2];
    const float* Ws1 = (const float*)d_in[3];
    const float* Wn1 = (const float*)d_in[4];
    const float* b1  = (const float*)d_in[5];
    const float* Ws2 = (const float*)d_in[6];
    const float* Wn2 = (const float*)d_in[7];
    const float* b2  = (const float*)d_in[8];
    float* out = (float*)d_out;

    // workspace layout (all offsets multiples of 64 ints = 256B)
    int* cnt      = (int*)d_ws;
    int* rowptr   = cnt    + ((N + 63) & ~63);
    int* cursor   = rowptr + ((N + 1 + 63) & ~63);
    int* edge_src = cursor + ((N + 63) & ~63);
    int* partials = edge_src + ((E + 63) & ~63);
    float* A      = (float*)(partials + 256);     // N*DF floats (h_neigh buffer)

    const int NB = (N + 1023) / 1024;   // 98 blocks, <= 256

    hipMemsetAsync(cnt, 0, (size_t)N * sizeof(int), stream);
    hist_kernel<<<(E + 255) / 256, 256, 0, stream>>>(dst, cnt, E);
    scan1_kernel<<<NB, 256, 0, stream>>>(cnt, partials, N);
    scan2_kernel<<<1, 256, 0, stream>>>(partials, NB);
    scan3_kernel<<<NB, 256, 0, stream>>>(cnt, partials, rowptr, cursor, N, E);
    scatter_kernel<<<(E + 255) / 256, 256, 0, stream>>>(src, dst, cursor, edge_src, E);

    const int aggGrid  = (N + 3) / 4;        // 4 nodes (waves) per 256-thread block
    const int gemmGrid = (N + 63) / 64;

    // layer 1
    aggregate_kernel<<<aggGrid, 256, 0, stream>>>(x, rowptr, edge_src, A, N);
    sage_gemm_kernel<<<gemmGrid, 256, 0, stream>>>(x, A, Ws1, Wn1, b1, out, N);
    // layer 2 (h1 lives in d_out; gemm2 runs in-place on its own rows)
    aggregate_kernel<<<aggGrid, 256, 0, stream>>>(out, rowptr, edge_src, A, N);
    sage_gemm_kernel<<<gemmGrid, 256, 0, stream>>>(out, A, Ws2, Wn2, b2, out, N);
}

// Round 2
// 463.343 us; speedup vs baseline: 1.8304x; 1.8304x over previous
//
#include <hip/hip_runtime.h>

#define DF 128

typedef __bf16 bf16x8_t __attribute__((ext_vector_type(8)));
typedef float f32x4_t __attribute__((ext_vector_type(4)));
typedef unsigned short ushort_t;
typedef ushort_t ushort8_t __attribute__((ext_vector_type(8)));

static __device__ __forceinline__ ushort_t f2bf(float f) {
    union { float f; unsigned int u; } v; v.f = f;
    unsigned int r = v.u + 0x7fffu + ((v.u >> 16) & 1u);   // RNE
    return (ushort_t)(r >> 16);
}
static __device__ __forceinline__ float bflo(unsigned int v) {
    union { unsigned int u; float f; } c; c.u = v << 16; return c.f;
}
static __device__ __forceinline__ float bfhi(unsigned int v) {
    union { unsigned int u; float f; } c; c.u = v & 0xffff0000u; return c.f;
}

// ---------------- CSR build ----------------
__global__ void hist_kernel(const int* __restrict__ dst, int* __restrict__ cnt, int E) {
    int e = blockIdx.x * blockDim.x + threadIdx.x;
    if (e < E) atomicAdd(&cnt[dst[e]], 1);
}

__global__ void scan1_kernel(const int* __restrict__ cnt, int* __restrict__ partials, int N) {
    __shared__ int sdata[256];
    int t = threadIdx.x;
    int base = blockIdx.x * 1024 + t * 4;
    int s = 0;
#pragma unroll
    for (int j = 0; j < 4; ++j) { int i = base + j; if (i < N) s += cnt[i]; }
    sdata[t] = s; __syncthreads();
    for (int off = 128; off > 0; off >>= 1) {
        if (t < off) sdata[t] += sdata[t + off];
        __syncthreads();
    }
    if (t == 0) partials[blockIdx.x] = sdata[0];
}

__global__ void scan2_kernel(int* partials, int NB) {
    __shared__ int sdata[256];
    int t = threadIdx.x;
    int v = (t < NB) ? partials[t] : 0;
    sdata[t] = v; __syncthreads();
    for (int off = 1; off < 256; off <<= 1) {
        int u = (t >= off) ? sdata[t - off] : 0;
        __syncthreads();
        sdata[t] += u;
        __syncthreads();
    }
    partials[t] = sdata[t] - v;  // exclusive
}

__global__ void scan3_kernel(const int* __restrict__ cnt, const int* __restrict__ partials,
                             int* __restrict__ rowptr, int* __restrict__ cursor, int N, int E) {
    __shared__ int sdata[256];
    int t = threadIdx.x;
    int base = blockIdx.x * 1024 + t * 4;
    int v[4]; int s = 0;
#pragma unroll
    for (int j = 0; j < 4; ++j) { int i = base + j; v[j] = (i < N) ? cnt[i] : 0; s += v[j]; }
    sdata[t] = s; __syncthreads();
    for (int off = 1; off < 256; off <<= 1) {
        int u = (t >= off) ? sdata[t - off] : 0;
        __syncthreads();
        sdata[t] += u;
        __syncthreads();
    }
    int run = partials[blockIdx.x] + sdata[t] - s;
#pragma unroll
    for (int j = 0; j < 4; ++j) {
        int i = base + j;
        if (i < N) { rowptr[i] = run; cursor[i] = run; run += v[j]; }
    }
    if (blockIdx.x == 0 && t == 0) rowptr[N] = E;
}

__global__ void scatter_kernel(const int* __restrict__ src, const int* __restrict__ dst,
                               int* __restrict__ cursor, int* __restrict__ edge_src, int E) {
    int e = blockIdx.x * blockDim.x + threadIdx.x;
    if (e < E) {
        int d = dst[e];
        int pos = atomicAdd(&cursor[d], 1);
        edge_src[pos] = src[e];
    }
}

// ---------------- x (fp32) -> bf16 ----------------
__global__ __launch_bounds__(256) void conv_bf16_kernel(const float* __restrict__ in,
                                                        ushort_t* __restrict__ out, int n8) {
    int i = blockIdx.x * blockDim.x + threadIdx.x;
    if (i >= n8) return;
    float4 a = ((const float4*)in)[(size_t)i * 2];
    float4 b = ((const float4*)in)[(size_t)i * 2 + 1];
    ushort8_t o;
    o[0] = f2bf(a.x); o[1] = f2bf(a.y); o[2] = f2bf(a.z); o[3] = f2bf(a.w);
    o[4] = f2bf(b.x); o[5] = f2bf(b.y); o[6] = f2bf(b.z); o[7] = f2bf(b.w);
    ((ushort8_t*)out)[i] = o;
}

// ---------------- W (fp32 [k][n]) -> W^T (bf16 [n][k]), 4 matrices ----------------
__global__ void transpose_w_kernel(const float* __restrict__ W0, const float* __restrict__ W1,
                                   const float* __restrict__ W2, const float* __restrict__ W3,
                                   ushort_t* __restrict__ out) {
    int m = blockIdx.x >> 6;  // 64 blocks per matrix
    const float* W = (m == 0) ? W0 : (m == 1) ? W1 : (m == 2) ? W2 : W3;
    int idx = (blockIdx.x & 63) * 256 + threadIdx.x;  // 0..16383
    int k = idx >> 7, n = idx & 127;
    out[m * 16384 + n * 128 + k] = f2bf(W[idx]);
}

// ---------------- mean aggregation (bf16 in/out): one wave per node ----------------
__global__ __launch_bounds__(256) void aggregate_bf16_kernel(
    const ushort_t* __restrict__ Xb, const int* __restrict__ rowptr,
    const int* __restrict__ edge_src, ushort_t* __restrict__ out, int N) {
    int node = (int)((blockIdx.x * 256u + threadIdx.x) >> 6);
    int lane = threadIdx.x & 63;
    if (node >= N) return;
    int beg = rowptr[node], end = rowptr[node + 1];
    float ax = 0.f, ay = 0.f;
    int e = beg;
    for (; e + 4 <= end; e += 4) {
        int s0 = edge_src[e + 0], s1 = edge_src[e + 1];
        int s2 = edge_src[e + 2], s3 = edge_src[e + 3];
        unsigned int v0 = *(const unsigned int*)(Xb + (size_t)s0 * DF + lane * 2);
        unsigned int v1 = *(const unsigned int*)(Xb + (size_t)s1 * DF + lane * 2);
        unsigned int v2 = *(const unsigned int*)(Xb + (size_t)s2 * DF + lane * 2);
        unsigned int v3 = *(const unsigned int*)(Xb + (size_t)s3 * DF + lane * 2);
        ax += bflo(v0) + bflo(v1) + bflo(v2) + bflo(v3);
        ay += bfhi(v0) + bfhi(v1) + bfhi(v2) + bfhi(v3);
    }
    for (; e < end; ++e) {
        unsigned int v = *(const unsigned int*)(Xb + (size_t)edge_src[e] * DF + lane * 2);
        ax += bflo(v); ay += bfhi(v);
    }
    float inv = 1.0f / fmaxf((float)(end - beg), 1.0f);
    unsigned int o = ((unsigned int)f2bf(ay * inv) << 16) | (unsigned int)f2bf(ax * inv);
    *(unsigned int*)(out + (size_t)node * DF + lane * 2) = o;
}

// ---------------- fused SAGE GEMM via MFMA ----------------
// out = relu(Xb@Ws^T' + Ab@Wn^T' + b).  A-frags direct from global (row-major bf16),
// B-frags direct from global W^T (col-major bf16, L1/L2-resident). No LDS, no barriers.
// Xb may alias out (in-place): each wave reads only its own 32 rows, all reads
// precede the epilogue stores; stores for rows >= M are guarded off.
template <int BF16OUT>
__global__ __launch_bounds__(256) void sage_mfma_kernel(
    const ushort_t* Xb, const ushort_t* __restrict__ Ab,
    const ushort_t* __restrict__ Wts, const ushort_t* __restrict__ Wtn,
    const float* __restrict__ bias, void* outv, int M) {
    const int lane = threadIdx.x & 63;
    const int w = threadIdx.x >> 6;
    const int l15 = lane & 15;
    const int g = lane >> 4;
    const int m0 = blockIdx.x * 128 + w * 32;

    f32x4_t acc[2][8];
#pragma unroll
    for (int rf = 0; rf < 2; ++rf)
#pragma unroll
        for (int c = 0; c < 8; ++c) acc[rf][c] = (f32x4_t){0.f, 0.f, 0.f, 0.f};

    int r0 = m0 + l15;      if (r0 >= M) r0 = M - 1;
    int r1 = m0 + 16 + l15; if (r1 >= M) r1 = M - 1;

    const ushort_t* Asrc = Xb;
    const ushort_t* Wsrc = Wts;
#pragma unroll
    for (int mat = 0; mat < 2; ++mat) {
#pragma unroll
        for (int ks = 0; ks < 4; ++ks) {
            const int ko = ks * 32 + g * 8;   // k-offset of this lane's 8 elems
            bf16x8_t a0 = *(const bf16x8_t*)(Asrc + (size_t)r0 * DF + ko);
            bf16x8_t a1 = *(const bf16x8_t*)(Asrc + (size_t)r1 * DF + ko);
#pragma unroll
            for (int c = 0; c < 8; ++c) {
                bf16x8_t b = *(const bf16x8_t*)(Wsrc + (size_t)(c * 16 + l15) * DF + ko);
                acc[0][c] = __builtin_amdgcn_mfma_f32_16x16x32_bf16(a0, b, acc[0][c], 0, 0, 0);
                acc[1][c] = __builtin_amdgcn_mfma_f32_16x16x32_bf16(a1, b, acc[1][c], 0, 0, 0);
            }
        }
        Asrc = Ab; Wsrc = Wtn;
    }

#pragma unroll
    for (int c = 0; c < 8; ++c) {
        int col = c * 16 + l15;
        float bv = bias[col];
#pragma unroll
        for (int rf = 0; rf < 2; ++rf)
#pragma unroll
            for (int j = 0; j < 4; ++j) {
                int row = m0 + rf * 16 + g * 4 + j;
                if (row < M) {
                    float v = fmaxf(acc[rf][c][j] + bv, 0.f);
                    if (BF16OUT) ((ushort_t*)outv)[(size_t)row * DF + col] = f2bf(v);
                    else         ((float*)outv)[(size_t)row * DF + col] = v;
                }
            }
    }
}

extern "C" void kernel_launch(void* const* d_in, const int* in_sizes, int n_in,
                              void* d_out, int out_size, void* d_ws, size_t ws_size,
                              hipStream_t stream) {
    const int N = in_sizes[0] / DF;   // 100000
    const int E = in_sizes[1];        // 1600000

    const float* x   = (const float*)d_in[0];
    const int*   src = (const int*)d_in[1];
    const int*   dst = (const int*)d_in[2];
    const float* Ws1 = (const float*)d_in[3];
    const float* Wn1 = (const float*)d_in[4];
    const float* b1  = (const float*)d_in[5];
    const float* Ws2 = (const float*)d_in[6];
    const float* Wn2 = (const float*)d_in[7];
    const float* b2  = (const float*)d_in[8];
    float* out = (float*)d_out;

    // workspace layout (identical footprint to R1: 58.8 MB)
    int* cnt      = (int*)d_ws;                       // dead after scan3 -> reused for W^T
    int* rowptr   = cnt    + ((N + 63) & ~63);
    int* cursor   = rowptr + ((N + 1 + 63) & ~63);
    int* edge_src = cursor + ((N + 63) & ~63);
    int* partials = edge_src + ((E + 63) & ~63);
    ushort_t* Xb  = (ushort_t*)(partials + 256);      // N*128 bf16 (becomes h1 in-place)
    ushort_t* Ab  = Xb + (size_t)N * DF;              // N*128 bf16 (h_neigh)
    ushort_t* Wt  = (ushort_t*)cnt;                   // 4 x 128x128 bf16 = 128 KB (over cnt)
    ushort_t* Wt1s = Wt, *Wt1n = Wt + 16384, *Wt2s = Wt + 32768, *Wt2n = Wt + 49152;

    const int NB = (N + 1023) / 1024;

    hipMemsetAsync(cnt, 0, (size_t)N * sizeof(int), stream);
    conv_bf16_kernel<<<(N * DF / 8 + 255) / 256, 256, 0, stream>>>(x, Xb, N * DF / 8);
    hist_kernel<<<(E + 255) / 256, 256, 0, stream>>>(dst, cnt, E);
    scan1_kernel<<<NB, 256, 0, stream>>>(cnt, partials, N);
    scan2_kernel<<<1, 256, 0, stream>>>(partials, NB);
    scan3_kernel<<<NB, 256, 0, stream>>>(cnt, partials, rowptr, cursor, N, E);
    scatter_kernel<<<(E + 255) / 256, 256, 0, stream>>>(src, dst, cursor, edge_src, E);
    // cnt is dead now; write W^T (bf16, col-major) over it
    transpose_w_kernel<<<256, 256, 0, stream>>>(Ws1, Wn1, Ws2, Wn2, Wt);

    const int aggGrid  = (N + 3) / 4;          // 4 waves (nodes) per block
    const int gemmGrid = (N + 127) / 128;      // 128 rows per block (4 waves x 32)

    // layer 1: agg(Xb) -> Ab ; h1 = relu(Xb@Ws1 + Ab@Wn1 + b1) written bf16 IN-PLACE over Xb
    aggregate_bf16_kernel<<<aggGrid, 256, 0, stream>>>(Xb, rowptr, edge_src, Ab, N);
    sage_mfma_kernel<1><<<gemmGrid, 256, 0, stream>>>(Xb, Ab, Wt1s, Wt1n, b1, (void*)Xb, N);
    // layer 2: agg(h1) -> Ab ; out = relu(h1@Ws2 + Ab@Wn2 + b2) fp32 to d_out
    aggregate_bf16_kernel<<<aggGrid, 256, 0, stream>>>(Xb, rowptr, edge_src, Ab, N);
    sage_mfma_kernel<0><<<gemmGrid, 256, 0, stream>>>(Xb, Ab, Wt2s, Wt2n, b2, (void*)out, N);
}

// Round 3
// 416.311 us; speedup vs baseline: 2.0372x; 1.1130x over previous
//
#include <hip/hip_runtime.h>

#define DF 128

typedef __bf16 bf16x8_t __attribute__((ext_vector_type(8)));
typedef float f32x4_t __attribute__((ext_vector_type(4)));
typedef unsigned short ushort_t;
typedef ushort_t ushort8_t __attribute__((ext_vector_type(8)));

static __device__ __forceinline__ ushort_t f2bf(float f) {
    union { float f; unsigned int u; } v; v.f = f;
    unsigned int r = v.u + 0x7fffu + ((v.u >> 16) & 1u);   // RNE
    return (ushort_t)(r >> 16);
}
static __device__ __forceinline__ float bflo(unsigned int v) {
    union { unsigned int u; float f; } c; c.u = v << 16; return c.f;
}
static __device__ __forceinline__ float bfhi(unsigned int v) {
    union { unsigned int u; float f; } c; c.u = v & 0xffff0000u; return c.f;
}

// ---------------- CSR build ----------------
__global__ void hist_kernel(const int* __restrict__ dst, int* __restrict__ cnt, int E) {
    int e = blockIdx.x * blockDim.x + threadIdx.x;
    if (e < E) atomicAdd(&cnt[dst[e]], 1);
}

__global__ void scan1_kernel(const int* __restrict__ cnt, int* __restrict__ partials, int N) {
    __shared__ int sdata[256];
    int t = threadIdx.x;
    int base = blockIdx.x * 1024 + t * 4;
    int s = 0;
#pragma unroll
    for (int j = 0; j < 4; ++j) { int i = base + j; if (i < N) s += cnt[i]; }
    sdata[t] = s; __syncthreads();
    for (int off = 128; off > 0; off >>= 1) {
        if (t < off) sdata[t] += sdata[t + off];
        __syncthreads();
    }
    if (t == 0) partials[blockIdx.x] = sdata[0];
}

__global__ void scan2_kernel(int* partials, int NB) {
    __shared__ int sdata[256];
    int t = threadIdx.x;
    int v = (t < NB) ? partials[t] : 0;
    sdata[t] = v; __syncthreads();
    for (int off = 1; off < 256; off <<= 1) {
        int u = (t >= off) ? sdata[t - off] : 0;
        __syncthreads();
        sdata[t] += u;
        __syncthreads();
    }
    partials[t] = sdata[t] - v;  // exclusive
}

__global__ void scan3_kernel(const int* __restrict__ cnt, const int* __restrict__ partials,
                             int* __restrict__ rowptr, int* __restrict__ cursor, int N, int E) {
    __shared__ int sdata[256];
    int t = threadIdx.x;
    int base = blockIdx.x * 1024 + t * 4;
    int v[4]; int s = 0;
#pragma unroll
    for (int j = 0; j < 4; ++j) { int i = base + j; v[j] = (i < N) ? cnt[i] : 0; s += v[j]; }
    sdata[t] = s; __syncthreads();
    for (int off = 1; off < 256; off <<= 1) {
        int u = (t >= off) ? sdata[t - off] : 0;
        __syncthreads();
        sdata[t] += u;
        __syncthreads();
    }
    int run = partials[blockIdx.x] + sdata[t] - s;
#pragma unroll
    for (int j = 0; j < 4; ++j) {
        int i = base + j;
        if (i < N) { rowptr[i] = run; cursor[i] = run; run += v[j]; }
    }
    if (blockIdx.x == 0 && t == 0) rowptr[N] = E;
}

// XCD-local scatter: block b (round-robin to XCD b&7) keeps only edges whose
// dst falls in its XCD's node range -> each edge_src cache line is written by
// exactly one XCD -> lines fill in local L2, writeback = compulsory 6.4 MB.
// Correctness does NOT depend on the b&7 == XCD heuristic (atomics give unique
// positions regardless); only locality does.
__global__ __launch_bounds__(256) void scatter_xcd_kernel(
    const int* __restrict__ src, const int* __restrict__ dst,
    int* __restrict__ cursor, int* __restrict__ edge_src,
    int E, int N, int chunkSize) {
    const int xcd = blockIdx.x & 7;
    const int j = blockIdx.x >> 3;
    const int lo = (int)(((long long)N * xcd) >> 3);
    const int hi = (int)(((long long)N * (xcd + 1)) >> 3);
    const int base = j * chunkSize;
    const int lim = min(base + chunkSize, E);
    for (int i = base + threadIdx.x; i < lim; i += 256) {
        int d = dst[i];
        if (d >= lo && d < hi) {
            int pos = atomicAdd(&cursor[d], 1);
            edge_src[pos] = src[i];
        }
    }
}

// ---------------- x (fp32) -> bf16 ----------------
__global__ __launch_bounds__(256) void conv_bf16_kernel(const float* __restrict__ in,
                                                        ushort_t* __restrict__ out, int n8) {
    int i = blockIdx.x * blockDim.x + threadIdx.x;
    if (i >= n8) return;
    float4 a = ((const float4*)in)[(size_t)i * 2];
    float4 b = ((const float4*)in)[(size_t)i * 2 + 1];
    ushort8_t o;
    o[0] = f2bf(a.x); o[1] = f2bf(a.y); o[2] = f2bf(a.z); o[3] = f2bf(a.w);
    o[4] = f2bf(b.x); o[5] = f2bf(b.y); o[6] = f2bf(b.z); o[7] = f2bf(b.w);
    ((ushort8_t*)out)[i] = o;
}

// ---------------- W (fp32 [k][n]) -> W^T (bf16 [n][k]), 4 matrices ----------------
__global__ void transpose_w_kernel(const float* __restrict__ W0, const float* __restrict__ W1,
                                   const float* __restrict__ W2, const float* __restrict__ W3,
                                   ushort_t* __restrict__ out) {
    int m = blockIdx.x >> 6;  // 64 blocks per matrix
    const float* W = (m == 0) ? W0 : (m == 1) ? W1 : (m == 2) ? W2 : W3;
    int idx = (blockIdx.x & 63) * 256 + threadIdx.x;  // 0..16383
    int k = idx >> 7, n = idx & 127;
    out[m * 16384 + n * 128 + k] = f2bf(W[idx]);
}

// ---------------- mean aggregation: 1 wave/node, 4 edges in parallel ----------------
// Wave = 4 groups x 16 lanes. Group g takes edges beg+g, beg+g+4, ...
// Each lane loads 16 B (8 bf16) of the gathered row -> 1 KB per wave load instr.
// Cross-group reduce via 2 shfl_xor; lanes 0-15 store 16 B each.
__global__ __launch_bounds__(256) void aggregate_bf16_kernel(
    const ushort_t* __restrict__ Xb, const int* __restrict__ rowptr,
    const int* __restrict__ edge_src, ushort_t* __restrict__ out, int N) {
    int node = (int)((blockIdx.x * 256u + threadIdx.x) >> 6);
    int lane = threadIdx.x & 63;
    if (node >= N) return;
    const int g = lane >> 4;
    const int s = lane & 15;
    int beg = rowptr[node], end = rowptr[node + 1];
    float acc[8] = {0.f, 0.f, 0.f, 0.f, 0.f, 0.f, 0.f, 0.f};
    for (int e = beg + g; e < end; e += 4) {
        int srcn = edge_src[e];
        uint4 v = *(const uint4*)(Xb + (size_t)srcn * DF + s * 8);
        acc[0] += bflo(v.x); acc[1] += bfhi(v.x);
        acc[2] += bflo(v.y); acc[3] += bfhi(v.y);
        acc[4] += bflo(v.z); acc[5] += bfhi(v.z);
        acc[6] += bflo(v.w); acc[7] += bfhi(v.w);
    }
#pragma unroll
    for (int i = 0; i < 8; ++i) {
        acc[i] += __shfl_xor(acc[i], 16, 64);
        acc[i] += __shfl_xor(acc[i], 32, 64);
    }
    if (g == 0) {
        float inv = 1.0f / fmaxf((float)(end - beg), 1.0f);
        ushort8_t o;
#pragma unroll
        for (int i = 0; i < 8; ++i) o[i] = f2bf(acc[i] * inv);
        *(ushort8_t*)(out + (size_t)node * DF + s * 8) = o;
    }
}

// ---------------- fused SAGE GEMM via MFMA ----------------
// out = relu(Xb@Ws^T' + Ab@Wn^T' + b).  A-frags direct from global (row-major bf16),
// B-frags direct from global W^T (col-major bf16, L1/L2-resident). No LDS, no barriers.
// Xb may alias out (in-place): each wave reads only its own 32 rows, all reads
// precede the epilogue stores; stores for rows >= M are guarded off.
template <int BF16OUT>
__global__ __launch_bounds__(256) void sage_mfma_kernel(
    const ushort_t* Xb, const ushort_t* __restrict__ Ab,
    const ushort_t* __restrict__ Wts, const ushort_t* __restrict__ Wtn,
    const float* __restrict__ bias, void* outv, int M) {
    const int lane = threadIdx.x & 63;
    const int w = threadIdx.x >> 6;
    const int l15 = lane & 15;
    const int g = lane >> 4;
    const int m0 = blockIdx.x * 128 + w * 32;

    f32x4_t acc[2][8];
#pragma unroll
    for (int rf = 0; rf < 2; ++rf)
#pragma unroll
        for (int c = 0; c < 8; ++c) acc[rf][c] = (f32x4_t){0.f, 0.f, 0.f, 0.f};

    int r0 = m0 + l15;      if (r0 >= M) r0 = M - 1;
    int r1 = m0 + 16 + l15; if (r1 >= M) r1 = M - 1;

    const ushort_t* Asrc = Xb;
    const ushort_t* Wsrc = Wts;
#pragma unroll
    for (int mat = 0; mat < 2; ++mat) {
#pragma unroll
        for (int ks = 0; ks < 4; ++ks) {
            const int ko = ks * 32 + g * 8;   // k-offset of this lane's 8 elems
            bf16x8_t a0 = *(const bf16x8_t*)(Asrc + (size_t)r0 * DF + ko);
            bf16x8_t a1 = *(const bf16x8_t*)(Asrc + (size_t)r1 * DF + ko);
#pragma unroll
            for (int c = 0; c < 8; ++c) {
                bf16x8_t b = *(const bf16x8_t*)(Wsrc + (size_t)(c * 16 + l15) * DF + ko);
                acc[0][c] = __builtin_amdgcn_mfma_f32_16x16x32_bf16(a0, b, acc[0][c], 0, 0, 0);
                acc[1][c] = __builtin_amdgcn_mfma_f32_16x16x32_bf16(a1, b, acc[1][c], 0, 0, 0);
            }
        }
        Asrc = Ab; Wsrc = Wtn;
    }

#pragma unroll
    for (int c = 0; c < 8; ++c) {
        int col = c * 16 + l15;
        float bv = bias[col];
#pragma unroll
        for (int rf = 0; rf < 2; ++rf)
#pragma unroll
            for (int j = 0; j < 4; ++j) {
                int row = m0 + rf * 16 + g * 4 + j;
                if (row < M) {
                    float v = fmaxf(acc[rf][c][j] + bv, 0.f);
                    if (BF16OUT) ((ushort_t*)outv)[(size_t)row * DF + col] = f2bf(v);
                    else         ((float*)outv)[(size_t)row * DF + col] = v;
                }
            }
    }
}

extern "C" void kernel_launch(void* const* d_in, const int* in_sizes, int n_in,
                              void* d_out, int out_size, void* d_ws, size_t ws_size,
                              hipStream_t stream) {
    const int N = in_sizes[0] / DF;   // 100000
    const int E = in_sizes[1];        // 1600000

    const float* x   = (const float*)d_in[0];
    const int*   src = (const int*)d_in[1];
    const int*   dst = (const int*)d_in[2];
    const float* Ws1 = (const float*)d_in[3];
    const float* Wn1 = (const float*)d_in[4];
    const float* b1  = (const float*)d_in[5];
    const float* Ws2 = (const float*)d_in[6];
    const float* Wn2 = (const float*)d_in[7];
    const float* b2  = (const float*)d_in[8];
    float* out = (float*)d_out;

    // workspace layout (identical footprint to R2: ~58.8 MB)
    int* cnt      = (int*)d_ws;                       // dead after scan3 -> reused for W^T
    int* rowptr   = cnt    + ((N + 63) & ~63);
    int* cursor   = rowptr + ((N + 1 + 63) & ~63);
    int* edge_src = cursor + ((N + 63) & ~63);
    int* partials = edge_src + ((E + 63) & ~63);
    ushort_t* Xb  = (ushort_t*)(partials + 256);      // N*128 bf16 (becomes h1 in-place)
    ushort_t* Ab  = Xb + (size_t)N * DF;              // N*128 bf16 (h_neigh)
    ushort_t* Wt  = (ushort_t*)cnt;                   // 4 x 128x128 bf16 = 128 KB (over cnt)
    ushort_t* Wt1s = Wt, *Wt1n = Wt + 16384, *Wt2s = Wt + 32768, *Wt2n = Wt + 49152;

    const int NB = (N + 1023) / 1024;

    hipMemsetAsync(cnt, 0, (size_t)N * sizeof(int), stream);
    conv_bf16_kernel<<<(N * DF / 8 + 255) / 256, 256, 0, stream>>>(x, Xb, N * DF / 8);
    hist_kernel<<<(E + 255) / 256, 256, 0, stream>>>(dst, cnt, E);
    scan1_kernel<<<NB, 256, 0, stream>>>(cnt, partials, N);
    scan2_kernel<<<1, 256, 0, stream>>>(partials, NB);
    scan3_kernel<<<NB, 256, 0, stream>>>(cnt, partials, rowptr, cursor, N, E);

    const int CH = 2048;                          // edges per chunk
    const int nchunk = (E + CH - 1) / CH;
    scatter_xcd_kernel<<<nchunk * 8, 256, 0, stream>>>(src, dst, cursor, edge_src, E, N, CH);

    // cnt is dead now; write W^T (bf16, col-major) over it
    transpose_w_kernel<<<256, 256, 0, stream>>>(Ws1, Wn1, Ws2, Wn2, Wt);

    const int aggGrid  = (N + 3) / 4;          // 4 waves (nodes) per block
    const int gemmGrid = (N + 127) / 128;      // 128 rows per block (4 waves x 32)

    // layer 1: agg(Xb) -> Ab ; h1 = relu(Xb@Ws1 + Ab@Wn1 + b1) written bf16 IN-PLACE over Xb
    aggregate_bf16_kernel<<<aggGrid, 256, 0, stream>>>(Xb, rowptr, edge_src, Ab, N);
    sage_mfma_kernel<1><<<gemmGrid, 256, 0, stream>>>(Xb, Ab, Wt1s, Wt1n, b1, (void*)Xb, N);
    // layer 2: agg(h1) -> Ab ; out = relu(h1@Ws2 + Ab@Wn2 + b2) fp32 to d_out
    aggregate_bf16_kernel<<<aggGrid, 256, 0, stream>>>(Xb, rowptr, edge_src, Ab, N);
    sage_mfma_kernel<0><<<gemmGrid, 256, 0, stream>>>(Xb, Ab, Wt2s, Wt2n, b2, (void*)out, N);
}

// Round 5
// 291.540 us; speedup vs baseline: 2.9090x; 1.4280x over previous
//
#include <hip/hip_runtime.h>

#define DF 128

typedef __bf16 bf16x8_t __attribute__((ext_vector_type(8)));
typedef float f32x4_t __attribute__((ext_vector_type(4)));
typedef unsigned short ushort_t;
typedef ushort_t ushort8_t __attribute__((ext_vector_type(8)));

static __device__ __forceinline__ ushort_t f2bf(float f) {
    union { float f; unsigned int u; } v; v.f = f;
    unsigned int r = v.u + 0x7fffu + ((v.u >> 16) & 1u);   // RNE
    return (ushort_t)(r >> 16);
}
static __device__ __forceinline__ float bflo(unsigned int v) {
    union { unsigned int u; float f; } c; c.u = v << 16; return c.f;
}
static __device__ __forceinline__ float bfhi(unsigned int v) {
    union { unsigned int u; float f; } c; c.u = v & 0xffff0000u; return c.f;
}

// ================= counting-sort CSR build (no global atomics) =================
// bucket = dst >> 8 (256 nodes/bucket). All random access stays in LDS.

// K1: per-chunk coarse histogram -> C[b][c]
__global__ __launch_bounds__(256) void k1_coarse_hist(
    const int* __restrict__ dst, int* __restrict__ C,
    int E, int CH, int NCH, int NBKT) {
    __shared__ int lcnt[512];
    const int c = blockIdx.x;
    for (int b = threadIdx.x; b < NBKT; b += 256) lcnt[b] = 0;
    __syncthreads();
    const int base = c * CH, lim = min(base + CH, E);
    for (int i = base + threadIdx.x; i < lim; i += 256)
        atomicAdd(&lcnt[dst[i] >> 8], 1);
    __syncthreads();
    for (int b = threadIdx.x; b < NBKT; b += 256) C[b * NCH + c] = lcnt[b];
}

// K2a: in-place exclusive scan of each bucket row (NCH <= 512); rowtot[b] = total
__global__ __launch_bounds__(512) void k2a_row_scan(
    int* __restrict__ C, int* __restrict__ rowtot, int NCH) {
    __shared__ int sd[512];
    const int b = blockIdx.x, t = threadIdx.x;
    int v = (t < NCH) ? C[b * NCH + t] : 0;
    sd[t] = v; __syncthreads();
    for (int off = 1; off < 512; off <<= 1) {
        int u = (t >= off) ? sd[t - off] : 0;
        __syncthreads();
        sd[t] += u;
        __syncthreads();
    }
    if (t < NCH) C[b * NCH + t] = sd[t] - v;   // exclusive within row
    if (t == 511) rowtot[b] = sd[511];
}

// K2b: exclusive scan of rowtot (NBKT <= 512) -> rowbase, sentinels
__global__ __launch_bounds__(512) void k2b_base_scan(
    const int* __restrict__ rowtot, int* __restrict__ rowbase,
    int* __restrict__ rowptr, int NBKT, int N, int E) {
    __shared__ int sd[512];
    const int t = threadIdx.x;
    int v = (t < NBKT) ? rowtot[t] : 0;
    sd[t] = v; __syncthreads();
    for (int off = 1; off < 512; off <<= 1) {
        int u = (t >= off) ? sd[t - off] : 0;
        __syncthreads();
        sd[t] += u;
        __syncthreads();
    }
    if (t < NBKT) rowbase[t] = sd[t] - v;
    if (t == 0) { rowbase[NBKT] = E; rowptr[N] = E; }
}

// K3: binned scatter of packed (dlocal<<24 | src) into contiguous per-(b,c) runs
__global__ __launch_bounds__(256) void k3_bin_scatter(
    const int* __restrict__ src, const int* __restrict__ dst,
    const int* __restrict__ C, const int* __restrict__ rowbase,
    unsigned int* __restrict__ inter, int E, int CH, int NCH, int NBKT) {
    __shared__ int cur[512];
    const int c = blockIdx.x;
    for (int b = threadIdx.x; b < NBKT; b += 256)
        cur[b] = rowbase[b] + C[b * NCH + c];
    __syncthreads();
    const int base = c * CH, lim = min(base + CH, E);
    for (int i = base + threadIdx.x; i < lim; i += 256) {
        int d = dst[i];
        int s = src[i];
        int pos = atomicAdd(&cur[d >> 8], 1);
        inter[pos] = ((unsigned int)(d & 255) << 24) | (unsigned int)s;
    }
}

// K4: per-bucket fine sort. Stage in LDS, per-node hist+scan, in-LDS scatter,
// coalesced stream-out. Writes rowptr slice. Fallback (count > CAP): two-pass
// streaming with direct global scatter (correct, slower; never hit for this input).
#define K4CAP 6144
__global__ __launch_bounds__(256) void k4_fine_scatter(
    const unsigned int* __restrict__ inter, const int* __restrict__ rowbase,
    int* __restrict__ edge_src, int* __restrict__ rowptr, int N) {
    __shared__ unsigned int stage[K4CAP];
    __shared__ unsigned int outv[K4CAP];
    __shared__ int lcnt[256], lofs[256], lrun[256];
    const int b = blockIdx.x, t = threadIdx.x;
    const int base = rowbase[b], count = rowbase[b + 1] - base;
    const int n0 = b << 8;
    const int nn = min(256, N - n0);

    lcnt[t] = 0; lrun[t] = 0;
    __syncthreads();

    if (count <= K4CAP) {
        for (int i = t; i < count; i += 256) {
            unsigned int v = inter[base + i];
            stage[i] = v;
            atomicAdd(&lcnt[v >> 24], 1);
        }
        __syncthreads();
        // exclusive scan of lcnt
        int cv = lcnt[t];
        lofs[t] = cv; __syncthreads();
        for (int off = 1; off < 256; off <<= 1) {
            int u = (t >= off) ? lofs[t - off] : 0;
            __syncthreads();
            lofs[t] += u;
            __syncthreads();
        }
        lofs[t] -= cv;   // exclusive
        if (t < nn) rowptr[n0 + t] = base + lofs[t];
        __syncthreads();
        for (int i = t; i < count; i += 256) {
            unsigned int v = stage[i];
            int dl = v >> 24;
            int p = lofs[dl] + atomicAdd(&lrun[dl], 1);
            outv[p] = v & 0xFFFFFFu;
        }
        __syncthreads();
        for (int i = t; i < count; i += 256) edge_src[base + i] = (int)outv[i];
    } else {
        // fallback: pass 1 hist, scan, pass 2 direct scatter
        for (int i = t; i < count; i += 256)
            atomicAdd(&lcnt[inter[base + i] >> 24], 1);
        __syncthreads();
        int cv = lcnt[t];
        lofs[t] = cv; __syncthreads();
        for (int off = 1; off < 256; off <<= 1) {
            int u = (t >= off) ? lofs[t - off] : 0;
            __syncthreads();
            lofs[t] += u;
            __syncthreads();
        }
        lofs[t] -= cv;
        if (t < nn) rowptr[n0 + t] = base + lofs[t];
        __syncthreads();
        for (int i = t; i < count; i += 256) {
            unsigned int v = inter[base + i];
            int dl = v >> 24;
            int p = atomicAdd(&lrun[dl], 1);
            edge_src[base + lofs[dl] + p] = (int)(v & 0xFFFFFFu);
        }
    }
}

// ---------------- x (fp32) -> bf16 ----------------
__global__ __launch_bounds__(256) void conv_bf16_kernel(const float* __restrict__ in,
                                                        ushort_t* __restrict__ out, int n8) {
    int i = blockIdx.x * blockDim.x + threadIdx.x;
    if (i >= n8) return;
    float4 a = ((const float4*)in)[(size_t)i * 2];
    float4 b = ((const float4*)in)[(size_t)i * 2 + 1];
    ushort8_t o;
    o[0] = f2bf(a.x); o[1] = f2bf(a.y); o[2] = f2bf(a.z); o[3] = f2bf(a.w);
    o[4] = f2bf(b.x); o[5] = f2bf(b.y); o[6] = f2bf(b.z); o[7] = f2bf(b.w);
    ((ushort8_t*)out)[i] = o;
}

// ---------------- W (fp32 [k][n]) -> W^T (bf16 [n][k]), 4 matrices ----------------
__global__ void transpose_w_kernel(const float* __restrict__ W0, const float* __restrict__ W1,
                                   const float* __restrict__ W2, const float* __restrict__ W3,
                                   ushort_t* __restrict__ out) {
    int m = blockIdx.x >> 6;  // 64 blocks per matrix
    const float* W = (m == 0) ? W0 : (m == 1) ? W1 : (m == 2) ? W2 : W3;
    int idx = (blockIdx.x & 63) * 256 + threadIdx.x;  // 0..16383
    int k = idx >> 7, n = idx & 127;
    out[m * 16384 + n * 128 + k] = f2bf(W[idx]);
}

// ---------------- mean aggregation: 1 wave/node, preloaded edge indices ----------------
// Wave preloads up to 64 edge indices with ONE coalesced load, broadcasts via shfl.
// 4 groups x 16 lanes process 4 edges concurrently; lane loads 16 B of the row.
// CROSS-LANE DISCIPLINE: the shfl executes with ALL 64 lanes active every
// iteration (uniform trip count nit); only the accumulation is predicated.
// (R4 bug: per-group trip counts made shfl read EXEC-inactive lanes -> 0.)
__global__ __launch_bounds__(256) void aggregate_bf16_kernel(
    const ushort_t* __restrict__ Xb, const int* __restrict__ rowptr,
    const int* __restrict__ edge_src, ushort_t* __restrict__ out, int N) {
    int node = (int)((blockIdx.x * 256u + threadIdx.x) >> 6);
    int lane = threadIdx.x & 63;
    if (node >= N) return;
    const int g = lane >> 4;
    const int s = lane & 15;
    int beg = rowptr[node], end = rowptr[node + 1];
    int deg = end - beg;
    float acc[8] = {0.f, 0.f, 0.f, 0.f, 0.f, 0.f, 0.f, 0.f};
    for (int b0 = 0; b0 < deg; b0 += 64) {
        int nb = min(64, deg - b0);
        int idx = (lane < nb) ? edge_src[beg + b0 + lane] : 0;
        int nit = (nb + 3) >> 2;              // uniform across the wave
        for (int it = 0; it < nit; ++it) {
            int j = g + it * 4;               // this group's edge slot
            int srcn = __shfl(idx, (j < nb) ? j : 0, 64);  // full wave active
            if (j < nb) {
                uint4 v = *(const uint4*)(Xb + (size_t)srcn * DF + s * 8);
                acc[0] += bflo(v.x); acc[1] += bfhi(v.x);
                acc[2] += bflo(v.y); acc[3] += bfhi(v.y);
                acc[4] += bflo(v.z); acc[5] += bfhi(v.z);
                acc[6] += bflo(v.w); acc[7] += bfhi(v.w);
            }
        }
    }
#pragma unroll
    for (int i = 0; i < 8; ++i) {
        acc[i] += __shfl_xor(acc[i], 16, 64);
        acc[i] += __shfl_xor(acc[i], 32, 64);
    }
    if (g == 0) {
        float inv = 1.0f / fmaxf((float)deg, 1.0f);
        ushort8_t o;
#pragma unroll
        for (int i = 0; i < 8; ++i) o[i] = f2bf(acc[i] * inv);
        *(ushort8_t*)(out + (size_t)node * DF + s * 8) = o;
    }
}

// ---------------- fused SAGE GEMM via MFMA ----------------
// out = relu(Xb@Ws^T' + Ab@Wn^T' + b). A-frags direct from global (row-major bf16),
// B-frags from global W^T (col-major bf16, L2-resident). No LDS, no barriers.
// Xb may alias out (in-place): each wave reads only its own 32 rows, all reads
// precede the epilogue stores.
template <int BF16OUT>
__global__ __launch_bounds__(256) void sage_mfma_kernel(
    const ushort_t* Xb, const ushort_t* __restrict__ Ab,
    const ushort_t* __restrict__ Wts, const ushort_t* __restrict__ Wtn,
    const float* __restrict__ bias, void* outv, int M) {
    const int lane = threadIdx.x & 63;
    const int w = threadIdx.x >> 6;
    const int l15 = lane & 15;
    const int g = lane >> 4;
    const int m0 = blockIdx.x * 128 + w * 32;

    f32x4_t acc[2][8];
#pragma unroll
    for (int rf = 0; rf < 2; ++rf)
#pragma unroll
        for (int c = 0; c < 8; ++c) acc[rf][c] = (f32x4_t){0.f, 0.f, 0.f, 0.f};

    int r0 = m0 + l15;      if (r0 >= M) r0 = M - 1;
    int r1 = m0 + 16 + l15; if (r1 >= M) r1 = M - 1;

    const ushort_t* Asrc = Xb;
    const ushort_t* Wsrc = Wts;
#pragma unroll
    for (int mat = 0; mat < 2; ++mat) {
#pragma unroll
        for (int ks = 0; ks < 4; ++ks) {
            const int ko = ks * 32 + g * 8;
            bf16x8_t a0 = *(const bf16x8_t*)(Asrc + (size_t)r0 * DF + ko);
            bf16x8_t a1 = *(const bf16x8_t*)(Asrc + (size_t)r1 * DF + ko);
#pragma unroll
            for (int c = 0; c < 8; ++c) {
                bf16x8_t b = *(const bf16x8_t*)(Wsrc + (size_t)(c * 16 + l15) * DF + ko);
                acc[0][c] = __builtin_amdgcn_mfma_f32_16x16x32_bf16(a0, b, acc[0][c], 0, 0, 0);
                acc[1][c] = __builtin_amdgcn_mfma_f32_16x16x32_bf16(a1, b, acc[1][c], 0, 0, 0);
            }
        }
        Asrc = Ab; Wsrc = Wtn;
    }

#pragma unroll
    for (int c = 0; c < 8; ++c) {
        int col = c * 16 + l15;
        float bv = bias[col];
#pragma unroll
        for (int rf = 0; rf < 2; ++rf)
#pragma unroll
            for (int j = 0; j < 4; ++j) {
                int row = m0 + rf * 16 + g * 4 + j;
                if (row < M) {
                    float v = fmaxf(acc[rf][c][j] + bv, 0.f);
                    if (BF16OUT) ((ushort_t*)outv)[(size_t)row * DF + col] = f2bf(v);
                    else         ((float*)outv)[(size_t)row * DF + col] = v;
                }
            }
    }
}

extern "C" void kernel_launch(void* const* d_in, const int* in_sizes, int n_in,
                              void* d_out, int out_size, void* d_ws, size_t ws_size,
                              hipStream_t stream) {
    const int N = in_sizes[0] / DF;   // 100000
    const int E = in_sizes[1];        // 1600000

    const float* x   = (const float*)d_in[0];
    const int*   src = (const int*)d_in[1];
    const int*   dst = (const int*)d_in[2];
    const float* Ws1 = (const float*)d_in[3];
    const float* Wn1 = (const float*)d_in[4];
    const float* b1  = (const float*)d_in[5];
    const float* Ws2 = (const float*)d_in[6];
    const float* Wn2 = (const float*)d_in[7];
    const float* b2  = (const float*)d_in[8];
    float* out = (float*)d_out;

    const int NBKT = (N + 255) >> 8;          // 391 (<=512 for this problem)
    int CH = 4096;
    int NCH = (E + CH - 1) / CH;
    while (NCH > 512) { CH <<= 1; NCH = (E + CH - 1) / CH; }   // keep scans single-block

    // workspace layout (~58.7 MB, same footprint as R3)
    int* rowptr   = (int*)d_ws;                                  // N+1
    int* rowbase  = rowptr + ((N + 1 + 63) & ~63);               // NBKT+1
    int* rowtot   = rowbase + ((NBKT + 1 + 63) & ~63);           // NBKT
    int* C        = rowtot + ((NBKT + 63) & ~63);                // NBKT*NCH
    ushort_t* Wt  = (ushort_t*)(C + ((NBKT * NCH + 63) & ~63));  // 4*16384 bf16
    int* edge_src = (int*)(Wt + 65536);                          // E
    ushort_t* Xb  = (ushort_t*)(edge_src + ((E + 63) & ~63));    // N*128 bf16
    ushort_t* Ab  = Xb + (size_t)N * DF;                         // N*128 bf16
    unsigned int* inter = (unsigned int*)Ab;                     // E u32, overlays Ab (dead then)

    conv_bf16_kernel<<<(N * DF / 8 + 255) / 256, 256, 0, stream>>>(x, Xb, N * DF / 8);
    k1_coarse_hist<<<NCH, 256, 0, stream>>>(dst, C, E, CH, NCH, NBKT);
    k2a_row_scan<<<NBKT, 512, 0, stream>>>(C, rowtot, NCH);
    k2b_base_scan<<<1, 512, 0, stream>>>(rowtot, rowbase, rowptr, NBKT, N, E);
    k3_bin_scatter<<<NCH, 256, 0, stream>>>(src, dst, C, rowbase, inter, E, CH, NCH, NBKT);
    k4_fine_scatter<<<NBKT, 256, 0, stream>>>(inter, rowbase, edge_src, rowptr, N);
    transpose_w_kernel<<<256, 256, 0, stream>>>(Ws1, Wn1, Ws2, Wn2, Wt);

    const int aggGrid  = (N + 3) / 4;
    const int gemmGrid = (N + 127) / 128;

    // layer 1: agg(Xb) -> Ab ; h1 = relu(Xb@Ws1 + Ab@Wn1 + b1) bf16 in-place over Xb
    aggregate_bf16_kernel<<<aggGrid, 256, 0, stream>>>(Xb, rowptr, edge_src, Ab, N);
    sage_mfma_kernel<1><<<gemmGrid, 256, 0, stream>>>(Xb, Ab, Wt, Wt + 16384, b1, (void*)Xb, N);
    // layer 2: agg(h1) -> Ab ; out = relu(h1@Ws2 + Ab@Wn2 + b2) fp32 to d_out
    aggregate_bf16_kernel<<<aggGrid, 256, 0, stream>>>(Xb, rowptr, edge_src, Ab, N);
    sage_mfma_kernel<0><<<gemmGrid, 256, 0, stream>>>(Xb, Ab, Wt + 32768, Wt + 49152, b2, (void*)out, N);
}

// Round 6
// 247.544 us; speedup vs baseline: 3.4260x; 1.1777x over previous
//
#include <hip/hip_runtime.h>

#define DF 128

typedef __bf16 bf16x8_t __attribute__((ext_vector_type(8)));
typedef float f32x4_t __attribute__((ext_vector_type(4)));
typedef unsigned short ushort_t;
typedef ushort_t ushort8_t __attribute__((ext_vector_type(8)));

static __device__ __forceinline__ ushort_t f2bf(float f) {
    union { float f; unsigned int u; } v; v.f = f;
    unsigned int r = v.u + 0x7fffu + ((v.u >> 16) & 1u);   // RNE
    return (ushort_t)(r >> 16);
}
static __device__ __forceinline__ float bflo(unsigned int v) {
    union { unsigned int u; float f; } c; c.u = v << 16; return c.f;
}
static __device__ __forceinline__ float bfhi(unsigned int v) {
    union { unsigned int u; float f; } c; c.u = v & 0xffff0000u; return c.f;
}

// ================= counting-sort CSR build (no global atomics) =================
// bucket = dst >> 8 (256 nodes/bucket). All random access stays in LDS.

__global__ __launch_bounds__(256) void k1_coarse_hist(
    const int* __restrict__ dst, int* __restrict__ C,
    int E, int CH, int NCH, int NBKT) {
    __shared__ int lcnt[512];
    const int c = blockIdx.x;
    for (int b = threadIdx.x; b < NBKT; b += 256) lcnt[b] = 0;
    __syncthreads();
    const int base = c * CH, lim = min(base + CH, E);
    for (int i = base + threadIdx.x; i < lim; i += 256)
        atomicAdd(&lcnt[dst[i] >> 8], 1);
    __syncthreads();
    for (int b = threadIdx.x; b < NBKT; b += 256) C[b * NCH + c] = lcnt[b];
}

__global__ __launch_bounds__(512) void k2a_row_scan(
    int* __restrict__ C, int* __restrict__ rowtot, int NCH) {
    __shared__ int sd[512];
    const int b = blockIdx.x, t = threadIdx.x;
    int v = (t < NCH) ? C[b * NCH + t] : 0;
    sd[t] = v; __syncthreads();
    for (int off = 1; off < 512; off <<= 1) {
        int u = (t >= off) ? sd[t - off] : 0;
        __syncthreads();
        sd[t] += u;
        __syncthreads();
    }
    if (t < NCH) C[b * NCH + t] = sd[t] - v;   // exclusive within row
    if (t == 511) rowtot[b] = sd[511];
}

__global__ __launch_bounds__(512) void k2b_base_scan(
    const int* __restrict__ rowtot, int* __restrict__ rowbase,
    int* __restrict__ rowptr, int NBKT, int N, int E) {
    __shared__ int sd[512];
    const int t = threadIdx.x;
    int v = (t < NBKT) ? rowtot[t] : 0;
    sd[t] = v; __syncthreads();
    for (int off = 1; off < 512; off <<= 1) {
        int u = (t >= off) ? sd[t - off] : 0;
        __syncthreads();
        sd[t] += u;
        __syncthreads();
    }
    if (t < NBKT) rowbase[t] = sd[t] - v;
    if (t == 0) { rowbase[NBKT] = E; rowptr[N] = E; }
}

__global__ __launch_bounds__(256) void k3_bin_scatter(
    const int* __restrict__ src, const int* __restrict__ dst,
    const int* __restrict__ C, const int* __restrict__ rowbase,
    unsigned int* __restrict__ inter, int E, int CH, int NCH, int NBKT) {
    __shared__ int cur[512];
    const int c = blockIdx.x;
    for (int b = threadIdx.x; b < NBKT; b += 256)
        cur[b] = rowbase[b] + C[b * NCH + c];
    __syncthreads();
    const int base = c * CH, lim = min(base + CH, E);
    for (int i = base + threadIdx.x; i < lim; i += 256) {
        int d = dst[i];
        int s = src[i];
        int pos = atomicAdd(&cur[d >> 8], 1);
        inter[pos] = ((unsigned int)(d & 255) << 24) | (unsigned int)s;
    }
}

#define K4CAP 6144
__global__ __launch_bounds__(256) void k4_fine_scatter(
    const unsigned int* __restrict__ inter, const int* __restrict__ rowbase,
    int* __restrict__ edge_src, int* __restrict__ rowptr, int N) {
    __shared__ unsigned int stage[K4CAP];
    __shared__ unsigned int outv[K4CAP];
    __shared__ int lcnt[256], lofs[256], lrun[256];
    const int b = blockIdx.x, t = threadIdx.x;
    const int base = rowbase[b], count = rowbase[b + 1] - base;
    const int n0 = b << 8;
    const int nn = min(256, N - n0);

    lcnt[t] = 0; lrun[t] = 0;
    __syncthreads();

    if (count <= K4CAP) {
        for (int i = t; i < count; i += 256) {
            unsigned int v = inter[base + i];
            stage[i] = v;
            atomicAdd(&lcnt[v >> 24], 1);
        }
        __syncthreads();
        int cv = lcnt[t];
        lofs[t] = cv; __syncthreads();
        for (int off = 1; off < 256; off <<= 1) {
            int u = (t >= off) ? lofs[t - off] : 0;
            __syncthreads();
            lofs[t] += u;
            __syncthreads();
        }
        lofs[t] -= cv;   // exclusive
        if (t < nn) rowptr[n0 + t] = base + lofs[t];
        __syncthreads();
        for (int i = t; i < count; i += 256) {
            unsigned int v = stage[i];
            int dl = v >> 24;
            int p = lofs[dl] + atomicAdd(&lrun[dl], 1);
            outv[p] = v & 0xFFFFFFu;
        }
        __syncthreads();
        for (int i = t; i < count; i += 256) edge_src[base + i] = (int)outv[i];
    } else {
        for (int i = t; i < count; i += 256)
            atomicAdd(&lcnt[inter[base + i] >> 24], 1);
        __syncthreads();
        int cv = lcnt[t];
        lofs[t] = cv; __syncthreads();
        for (int off = 1; off < 256; off <<= 1) {
            int u = (t >= off) ? lofs[t - off] : 0;
            __syncthreads();
            lofs[t] += u;
            __syncthreads();
        }
        lofs[t] -= cv;
        if (t < nn) rowptr[n0 + t] = base + lofs[t];
        __syncthreads();
        for (int i = t; i < count; i += 256) {
            unsigned int v = inter[base + i];
            int dl = v >> 24;
            int p = atomicAdd(&lrun[dl], 1);
            edge_src[base + lofs[dl] + p] = (int)(v & 0xFFFFFFu);
        }
    }
}

// ---------------- x (fp32) -> bf16 ----------------
__global__ __launch_bounds__(256) void conv_bf16_kernel(const float* __restrict__ in,
                                                        ushort_t* __restrict__ out, int n8) {
    int i = blockIdx.x * blockDim.x + threadIdx.x;
    if (i >= n8) return;
    float4 a = ((const float4*)in)[(size_t)i * 2];
    float4 b = ((const float4*)in)[(size_t)i * 2 + 1];
    ushort8_t o;
    o[0] = f2bf(a.x); o[1] = f2bf(a.y); o[2] = f2bf(a.z); o[3] = f2bf(a.w);
    o[4] = f2bf(b.x); o[5] = f2bf(b.y); o[6] = f2bf(b.z); o[7] = f2bf(b.w);
    ((ushort8_t*)out)[i] = o;
}

// ---------------- W (fp32 [k][n]) -> W^T (bf16 [n][k]), 4 matrices ----------------
__global__ void transpose_w_kernel(const float* __restrict__ W0, const float* __restrict__ W1,
                                   const float* __restrict__ W2, const float* __restrict__ W3,
                                   ushort_t* __restrict__ out) {
    int m = blockIdx.x >> 6;
    const float* W = (m == 0) ? W0 : (m == 1) ? W1 : (m == 2) ? W2 : W3;
    int idx = (blockIdx.x & 63) * 256 + threadIdx.x;
    int k = idx >> 7, n = idx & 127;
    out[m * 16384 + n * 128 + k] = f2bf(W[idx]);
}

// ---------------- mean aggregation: 1 wave/node, preloaded edge indices ----------------
// CROSS-LANE DISCIPLINE: shfl executes with all 64 lanes active (uniform trip
// count); only the accumulation is predicated (R4 lesson).
__global__ __launch_bounds__(256) void aggregate_bf16_kernel(
    const ushort_t* __restrict__ Xb, const int* __restrict__ rowptr,
    const int* __restrict__ edge_src, ushort_t* __restrict__ out, int N) {
    int node = (int)((blockIdx.x * 256u + threadIdx.x) >> 6);
    int lane = threadIdx.x & 63;
    if (node >= N) return;
    const int g = lane >> 4;
    const int s = lane & 15;
    int beg = rowptr[node], end = rowptr[node + 1];
    int deg = end - beg;
    float acc[8] = {0.f, 0.f, 0.f, 0.f, 0.f, 0.f, 0.f, 0.f};
    for (int b0 = 0; b0 < deg; b0 += 64) {
        int nb = min(64, deg - b0);
        int idx = (lane < nb) ? edge_src[beg + b0 + lane] : 0;
        int nit = (nb + 3) >> 2;              // uniform across the wave
        for (int it = 0; it < nit; ++it) {
            int j = g + it * 4;
            int srcn = __shfl(idx, (j < nb) ? j : 0, 64);  // full wave active
            if (j < nb) {
                uint4 v = *(const uint4*)(Xb + (size_t)srcn * DF + s * 8);
                acc[0] += bflo(v.x); acc[1] += bfhi(v.x);
                acc[2] += bflo(v.y); acc[3] += bfhi(v.y);
                acc[4] += bflo(v.z); acc[5] += bfhi(v.z);
                acc[6] += bflo(v.w); acc[7] += bfhi(v.w);
            }
        }
    }
#pragma unroll
    for (int i = 0; i < 8; ++i) {
        acc[i] += __shfl_xor(acc[i], 16, 64);
        acc[i] += __shfl_xor(acc[i], 32, 64);
    }
    if (g == 0) {
        float inv = 1.0f / fmaxf((float)deg, 1.0f);
        ushort8_t o;
#pragma unroll
        for (int i = 0; i < 8; ++i) o[i] = f2bf(acc[i] * inv);
        *(ushort8_t*)(out + (size_t)node * DF + s * 8) = o;
    }
}

// ---------------- fused SAGE GEMM via MFMA, W^T staged in swizzled LDS ----------------
// out = relu(Xb@Ws^T' + Ab@Wn^T' + b). A-frags stream from global; B-frags from
// LDS (64 KB, XOR-swizzled: byte ^= (row&7)<<4 -> 2-way bank aliasing = free).
// Xb may alias out (in-place): each wave reads only its own 32 rows, all reads
// precede the epilogue stores.
template <int BF16OUT>
__global__ __launch_bounds__(256) void sage_mfma_kernel(
    const ushort_t* Xb, const ushort_t* __restrict__ Ab,
    const ushort_t* __restrict__ Wts, const ushort_t* __restrict__ Wtn,
    const float* __restrict__ bias, void* outv, int M) {
    __shared__ ushort_t sW[32768];   // 64 KB: [mat(2)][row(128)][k(128)] bf16, swizzled

    // stage both W^T matrices, coalesced 16B units; swizzle on write
    for (int u = threadIdx.x; u < 4096; u += 256) {
        int row = u >> 4;                 // 0..255 (mat = row>>7)
        int kb  = (u & 15) << 4;          // byte offset within 256B row
        int swz = kb ^ ((row & 7) << 4);
        const ushort_t* gp = (row < 128)
            ? (Wts + ((size_t)row << 7) + (kb >> 1))
            : (Wtn + ((size_t)(row - 128) << 7) + (kb >> 1));
        *(ushort8_t*)((char*)sW + row * 256 + swz) = *(const ushort8_t*)gp;
    }
    __syncthreads();

    const int lane = threadIdx.x & 63;
    const int w = threadIdx.x >> 6;
    const int l15 = lane & 15;
    const int g = lane >> 4;
    const int m0 = blockIdx.x * 128 + w * 32;

    f32x4_t acc[2][8];
#pragma unroll
    for (int rf = 0; rf < 2; ++rf)
#pragma unroll
        for (int c = 0; c < 8; ++c) acc[rf][c] = (f32x4_t){0.f, 0.f, 0.f, 0.f};

    int r0 = m0 + l15;      if (r0 >= M) r0 = M - 1;
    int r1 = m0 + 16 + l15; if (r1 >= M) r1 = M - 1;

    const ushort_t* Asrc = Xb;
#pragma unroll
    for (int mat = 0; mat < 2; ++mat) {
#pragma unroll
        for (int ks = 0; ks < 4; ++ks) {
            const int ko = ks * 32 + g * 8;   // k-offset (elems) of this lane's 8
            bf16x8_t a0 = *(const bf16x8_t*)(Asrc + (size_t)r0 * DF + ko);
            bf16x8_t a1 = *(const bf16x8_t*)(Asrc + (size_t)r1 * DF + ko);
            const int kb = ks * 64 + g * 16;  // byte offset within row
#pragma unroll
            for (int c = 0; c < 8; ++c) {
                int brow = mat * 128 + c * 16 + l15;
                bf16x8_t b = *(const bf16x8_t*)((const char*)sW + brow * 256 +
                                                (kb ^ ((brow & 7) << 4)));
                acc[0][c] = __builtin_amdgcn_mfma_f32_16x16x32_bf16(a0, b, acc[0][c], 0, 0, 0);
                acc[1][c] = __builtin_amdgcn_mfma_f32_16x16x32_bf16(a1, b, acc[1][c], 0, 0, 0);
            }
        }
        Asrc = Ab;
    }

#pragma unroll
    for (int c = 0; c < 8; ++c) {
        int col = c * 16 + l15;
        float bv = bias[col];
#pragma unroll
        for (int rf = 0; rf < 2; ++rf)
#pragma unroll
            for (int j = 0; j < 4; ++j) {
                int row = m0 + rf * 16 + g * 4 + j;
                if (row < M) {
                    float v = fmaxf(acc[rf][c][j] + bv, 0.f);
                    if (BF16OUT) ((ushort_t*)outv)[(size_t)row * DF + col] = f2bf(v);
                    else         ((float*)outv)[(size_t)row * DF + col] = v;
                }
            }
    }
}

extern "C" void kernel_launch(void* const* d_in, const int* in_sizes, int n_in,
                              void* d_out, int out_size, void* d_ws, size_t ws_size,
                              hipStream_t stream) {
    const int N = in_sizes[0] / DF;   // 100000
    const int E = in_sizes[1];        // 1600000

    const float* x   = (const float*)d_in[0];
    const int*   src = (const int*)d_in[1];
    const int*   dst = (const int*)d_in[2];
    const float* Ws1 = (const float*)d_in[3];
    const float* Wn1 = (const float*)d_in[4];
    const float* b1  = (const float*)d_in[5];
    const float* Ws2 = (const float*)d_in[6];
    const float* Wn2 = (const float*)d_in[7];
    const float* b2  = (const float*)d_in[8];
    float* out = (float*)d_out;

    const int NBKT = (N + 255) >> 8;          // 391 (<=512 for this problem)
    int CH = 4096;
    int NCH = (E + CH - 1) / CH;
    while (NCH > 512) { CH <<= 1; NCH = (E + CH - 1) / CH; }

    // workspace layout (~58.7 MB)
    int* rowptr   = (int*)d_ws;                                  // N+1
    int* rowbase  = rowptr + ((N + 1 + 63) & ~63);               // NBKT+1
    int* rowtot   = rowbase + ((NBKT + 1 + 63) & ~63);           // NBKT
    int* C        = rowtot + ((NBKT + 63) & ~63);                // NBKT*NCH
    ushort_t* Wt  = (ushort_t*)(C + ((NBKT * NCH + 63) & ~63));  // 4*16384 bf16
    int* edge_src = (int*)(Wt + 65536);                          // E
    ushort_t* Xb  = (ushort_t*)(edge_src + ((E + 63) & ~63));    // N*128 bf16
    ushort_t* Ab  = Xb + (size_t)N * DF;                         // N*128 bf16
    unsigned int* inter = (unsigned int*)Ab;                     // E u32 (dead before Ab use)

    conv_bf16_kernel<<<(N * DF / 8 + 255) / 256, 256, 0, stream>>>(x, Xb, N * DF / 8);
    k1_coarse_hist<<<NCH, 256, 0, stream>>>(dst, C, E, CH, NCH, NBKT);
    k2a_row_scan<<<NBKT, 512, 0, stream>>>(C, rowtot, NCH);
    k2b_base_scan<<<1, 512, 0, stream>>>(rowtot, rowbase, rowptr, NBKT, N, E);
    k3_bin_scatter<<<NCH, 256, 0, stream>>>(src, dst, C, rowbase, inter, E, CH, NCH, NBKT);
    k4_fine_scatter<<<NBKT, 256, 0, stream>>>(inter, rowbase, edge_src, rowptr, N);
    transpose_w_kernel<<<256, 256, 0, stream>>>(Ws1, Wn1, Ws2, Wn2, Wt);

    const int aggGrid  = (N + 3) / 4;
    const int gemmGrid = (N + 127) / 128;

    // layer 1: agg(Xb) -> Ab ; h1 = relu(Xb@Ws1 + Ab@Wn1 + b1) bf16 in-place over Xb
    aggregate_bf16_kernel<<<aggGrid, 256, 0, stream>>>(Xb, rowptr, edge_src, Ab, N);
    sage_mfma_kernel<1><<<gemmGrid, 256, 0, stream>>>(Xb, Ab, Wt, Wt + 16384, b1, (void*)Xb, N);
    // layer 2: agg(h1) -> Ab ; out = relu(h1@Ws2 + Ab@Wn2 + b2) fp32 to d_out
    aggregate_bf16_kernel<<<aggGrid, 256, 0, stream>>>(Xb, rowptr, edge_src, Ab, N);
    sage_mfma_kernel<0><<<gemmGrid, 256, 0, stream>>>(Xb, Ab, Wt + 32768, Wt + 49152, b2, (void*)out, N);
}

// Round 7
// 219.127 us; speedup vs baseline: 3.8703x; 1.1297x over previous
//
#include <hip/hip_runtime.h>

#define DF 128

typedef __bf16 bf16x8_t __attribute__((ext_vector_type(8)));
typedef float f32x4_t __attribute__((ext_vector_type(4)));
typedef unsigned short ushort_t;
typedef ushort_t ushort8_t __attribute__((ext_vector_type(8)));

static __device__ __forceinline__ ushort_t f2bf(float f) {
    union { float f; unsigned int u; } v; v.f = f;
    unsigned int r = v.u + 0x7fffu + ((v.u >> 16) & 1u);   // RNE
    return (ushort_t)(r >> 16);
}
static __device__ __forceinline__ float bflo(unsigned int v) {
    union { unsigned int u; float f; } c; c.u = v << 16; return c.f;
}
static __device__ __forceinline__ float bfhi(unsigned int v) {
    union { unsigned int u; float f; } c; c.u = v & 0xffff0000u; return c.f;
}

// ================= counting-sort CSR build (no global atomics) =================
// bucket = dst >> 8 (256 nodes/bucket). All random access stays in LDS.

__global__ __launch_bounds__(256) void k1_coarse_hist(
    const int* __restrict__ dst, int* __restrict__ C,
    int E, int CH, int NCH, int NBKT) {
    __shared__ int lcnt[512];
    const int c = blockIdx.x;
    for (int b = threadIdx.x; b < NBKT; b += 256) lcnt[b] = 0;
    __syncthreads();
    const int base = c * CH, lim = min(base + CH, E);
    for (int i = base + threadIdx.x; i < lim; i += 256)
        atomicAdd(&lcnt[dst[i] >> 8], 1);
    __syncthreads();
    for (int b = threadIdx.x; b < NBKT; b += 256) C[b * NCH + c] = lcnt[b];
}

__global__ __launch_bounds__(512) void k2a_row_scan(
    int* __restrict__ C, int* __restrict__ rowtot, int NCH) {
    __shared__ int sd[512];
    const int b = blockIdx.x, t = threadIdx.x;
    int v = (t < NCH) ? C[b * NCH + t] : 0;
    sd[t] = v; __syncthreads();
    for (int off = 1; off < 512; off <<= 1) {
        int u = (t >= off) ? sd[t - off] : 0;
        __syncthreads();
        sd[t] += u;
        __syncthreads();
    }
    if (t < NCH) C[b * NCH + t] = sd[t] - v;   // exclusive within row
    if (t == 511) rowtot[b] = sd[511];
}

__global__ __launch_bounds__(512) void k2b_base_scan(
    const int* __restrict__ rowtot, int* __restrict__ rowbase,
    int* __restrict__ rowptr, int NBKT, int N, int E) {
    __shared__ int sd[512];
    const int t = threadIdx.x;
    int v = (t < NBKT) ? rowtot[t] : 0;
    sd[t] = v; __syncthreads();
    for (int off = 1; off < 512; off <<= 1) {
        int u = (t >= off) ? sd[t - off] : 0;
        __syncthreads();
        sd[t] += u;
        __syncthreads();
    }
    if (t < NBKT) rowbase[t] = sd[t] - v;
    if (t == 0) { rowbase[NBKT] = E; rowptr[N] = E; }
}

__global__ __launch_bounds__(256) void k3_bin_scatter(
    const int* __restrict__ src, const int* __restrict__ dst,
    const int* __restrict__ C, const int* __restrict__ rowbase,
    unsigned int* __restrict__ inter, int E, int CH, int NCH, int NBKT) {
    __shared__ int cur[512];
    const int c = blockIdx.x;
    for (int b = threadIdx.x; b < NBKT; b += 256)
        cur[b] = rowbase[b] + C[b * NCH + c];
    __syncthreads();
    const int base = c * CH, lim = min(base + CH, E);
    for (int i = base + threadIdx.x; i < lim; i += 256) {
        int d = dst[i];
        int s = src[i];
        int pos = atomicAdd(&cur[d >> 8], 1);
        inter[pos] = ((unsigned int)(d & 255) << 24) | (unsigned int)s;
    }
}

#define K4CAP 6144
__global__ __launch_bounds__(256) void k4_fine_scatter(
    const unsigned int* __restrict__ inter, const int* __restrict__ rowbase,
    int* __restrict__ edge_src, int* __restrict__ rowptr, int N) {
    __shared__ unsigned int stage[K4CAP];
    __shared__ unsigned int outv[K4CAP];
    __shared__ int lcnt[256], lofs[256], lrun[256];
    const int b = blockIdx.x, t = threadIdx.x;
    const int base = rowbase[b], count = rowbase[b + 1] - base;
    const int n0 = b << 8;
    const int nn = min(256, N - n0);

    lcnt[t] = 0; lrun[t] = 0;
    __syncthreads();

    if (count <= K4CAP) {
        for (int i = t; i < count; i += 256) {
            unsigned int v = inter[base + i];
            stage[i] = v;
            atomicAdd(&lcnt[v >> 24], 1);
        }
        __syncthreads();
        int cv = lcnt[t];
        lofs[t] = cv; __syncthreads();
        for (int off = 1; off < 256; off <<= 1) {
            int u = (t >= off) ? lofs[t - off] : 0;
            __syncthreads();
            lofs[t] += u;
            __syncthreads();
        }
        lofs[t] -= cv;   // exclusive
        if (t < nn) rowptr[n0 + t] = base + lofs[t];
        __syncthreads();
        for (int i = t; i < count; i += 256) {
            unsigned int v = stage[i];
            int dl = v >> 24;
            int p = lofs[dl] + atomicAdd(&lrun[dl], 1);
            outv[p] = v & 0xFFFFFFu;
        }
        __syncthreads();
        for (int i = t; i < count; i += 256) edge_src[base + i] = (int)outv[i];
    } else {
        for (int i = t; i < count; i += 256)
            atomicAdd(&lcnt[inter[base + i] >> 24], 1);
        __syncthreads();
        int cv = lcnt[t];
        lofs[t] = cv; __syncthreads();
        for (int off = 1; off < 256; off <<= 1) {
            int u = (t >= off) ? lofs[t - off] : 0;
            __syncthreads();
            lofs[t] += u;
            __syncthreads();
        }
        lofs[t] -= cv;
        if (t < nn) rowptr[n0 + t] = base + lofs[t];
        __syncthreads();
        for (int i = t; i < count; i += 256) {
            unsigned int v = inter[base + i];
            int dl = v >> 24;
            int p = atomicAdd(&lrun[dl], 1);
            edge_src[base + lofs[dl] + p] = (int)(v & 0xFFFFFFu);
        }
    }
}

// ---------------- x (fp32) -> bf16 ----------------
__global__ __launch_bounds__(256) void conv_bf16_kernel(const float* __restrict__ in,
                                                        ushort_t* __restrict__ out, int n8) {
    int i = blockIdx.x * blockDim.x + threadIdx.x;
    if (i >= n8) return;
    float4 a = ((const float4*)in)[(size_t)i * 2];
    float4 b = ((const float4*)in)[(size_t)i * 2 + 1];
    ushort8_t o;
    o[0] = f2bf(a.x); o[1] = f2bf(a.y); o[2] = f2bf(a.z); o[3] = f2bf(a.w);
    o[4] = f2bf(b.x); o[5] = f2bf(b.y); o[6] = f2bf(b.z); o[7] = f2bf(b.w);
    ((ushort8_t*)out)[i] = o;
}

// ---------------- W (fp32 [k][n]) -> W^T (bf16 [n][k]), 4 matrices ----------------
__global__ void transpose_w_kernel(const float* __restrict__ W0, const float* __restrict__ W1,
                                   const float* __restrict__ W2, const float* __restrict__ W3,
                                   ushort_t* __restrict__ out) {
    int m = blockIdx.x >> 6;
    const float* W = (m == 0) ? W0 : (m == 1) ? W1 : (m == 2) ? W2 : W3;
    int idx = (blockIdx.x & 63) * 256 + threadIdx.x;
    int k = idx >> 7, n = idx & 127;
    out[m * 16384 + n * 128 + k] = f2bf(W[idx]);
}

// ---------------- mean aggregation: 1 wave/node, 2 edges/group in flight ----------------
// 4 groups x 16 lanes; each group processes 2 edges per iteration (8/wave/iter).
// Main loop is predicate-free (full groups of 8); single wave-uniform tail iter.
// CROSS-LANE DISCIPLINE: shfl always executes with all 64 lanes active (R4 lesson).
// __launch_bounds__(256,4): 128-VGPR cap so the uint4 gathers + acc stay in regs
// (R6: default codegen chose 16 VGPRs and scalarized everything).
__global__ __launch_bounds__(256, 4) void aggregate_bf16_kernel(
    const ushort_t* __restrict__ Xb, const int* __restrict__ rowptr,
    const int* __restrict__ edge_src, ushort_t* __restrict__ out, int N) {
    int node = (int)((blockIdx.x * 256u + threadIdx.x) >> 6);
    int lane = threadIdx.x & 63;
    if (node >= N) return;
    const int g = lane >> 4;
    const int s = lane & 15;
    int beg = rowptr[node], end = rowptr[node + 1];
    int deg = end - beg;
    float acc[8] = {0.f, 0.f, 0.f, 0.f, 0.f, 0.f, 0.f, 0.f};
    for (int b0 = 0; b0 < deg; b0 += 64) {
        int nb = min(64, deg - b0);
        int idx = (lane < nb) ? edge_src[beg + b0 + lane] : 0;
        int nfull = nb >> 3;
        for (int it = 0; it < nfull; ++it) {
            int j0 = g + it * 8;
            int s0 = __shfl(idx, j0, 64);
            int s1 = __shfl(idx, j0 + 4, 64);
            uint4 v0 = *(const uint4*)(Xb + (size_t)s0 * DF + s * 8);
            uint4 v1 = *(const uint4*)(Xb + (size_t)s1 * DF + s * 8);
            acc[0] += bflo(v0.x) + bflo(v1.x); acc[1] += bfhi(v0.x) + bfhi(v1.x);
            acc[2] += bflo(v0.y) + bflo(v1.y); acc[3] += bfhi(v0.y) + bfhi(v1.y);
            acc[4] += bflo(v0.z) + bflo(v1.z); acc[5] += bfhi(v0.z) + bfhi(v1.z);
            acc[6] += bflo(v0.w) + bflo(v1.w); acc[7] += bfhi(v0.w) + bfhi(v1.w);
        }
        if (nb & 7) {   // wave-uniform tail: up to 7 edges, predicated consumers
            int j0 = g + nfull * 8;
            int j1 = j0 + 4;
            int s0 = __shfl(idx, (j0 < nb) ? j0 : 0, 64);   // full wave active
            int s1 = __shfl(idx, (j1 < nb) ? j1 : 0, 64);
            uint4 v0 = make_uint4(0, 0, 0, 0), v1 = make_uint4(0, 0, 0, 0);
            if (j0 < nb) v0 = *(const uint4*)(Xb + (size_t)s0 * DF + s * 8);
            if (j1 < nb) v1 = *(const uint4*)(Xb + (size_t)s1 * DF + s * 8);
            acc[0] += bflo(v0.x) + bflo(v1.x); acc[1] += bfhi(v0.x) + bfhi(v1.x);
            acc[2] += bflo(v0.y) + bflo(v1.y); acc[3] += bfhi(v0.y) + bfhi(v1.y);
            acc[4] += bflo(v0.z) + bflo(v1.z); acc[5] += bfhi(v0.z) + bfhi(v1.z);
            acc[6] += bflo(v0.w) + bflo(v1.w); acc[7] += bfhi(v0.w) + bfhi(v1.w);
        }
    }
#pragma unroll
    for (int i = 0; i < 8; ++i) {
        acc[i] += __shfl_xor(acc[i], 16, 64);
        acc[i] += __shfl_xor(acc[i], 32, 64);
    }
    if (g == 0) {
        float inv = 1.0f / fmaxf((float)deg, 1.0f);
        ushort8_t o;
#pragma unroll
        for (int i = 0; i < 8; ++i) o[i] = f2bf(acc[i] * inv);
        *(ushort8_t*)(out + (size_t)node * DF + s * 8) = o;
    }
}

// ---------------- fused SAGE GEMM via MFMA, W^T in swizzled LDS ----------------
// out = relu(Xb@Ws^T' + Ab@Wn^T' + b). ALL 16 A-fragments preloaded to registers
// before the W barrier (overlaps staging; one latency for the wave's A-needs).
// __launch_bounds__(256,2): 256-VGPR cap (R6's default chose 72 and serialized).
// Xb may alias out (in-place): reads complete before epilogue stores.
template <int BF16OUT>
__global__ __launch_bounds__(256, 2) void sage_mfma_kernel(
    const ushort_t* Xb, const ushort_t* __restrict__ Ab,
    const ushort_t* __restrict__ Wts, const ushort_t* __restrict__ Wtn,
    const float* __restrict__ bias, void* outv, int M) {
    __shared__ ushort_t sW[32768];   // 64 KB: [mat(2)][row(128)][k(128)] bf16, swizzled

    const int lane = threadIdx.x & 63;
    const int w = threadIdx.x >> 6;
    const int l15 = lane & 15;
    const int g = lane >> 4;
    const int m0 = blockIdx.x * 128 + w * 32;

    int r0 = m0 + l15;      if (r0 >= M) r0 = M - 1;
    int r1 = m0 + 16 + l15; if (r1 >= M) r1 = M - 1;

    // stage both W^T matrices into LDS (swizzle on write: byte ^= (row&7)<<4)
    for (int u = threadIdx.x; u < 4096; u += 256) {
        int row = u >> 4;
        int kb  = (u & 15) << 4;
        int swz = kb ^ ((row & 7) << 4);
        const ushort_t* gp = (row < 128)
            ? (Wts + ((size_t)row << 7) + (kb >> 1))
            : (Wtn + ((size_t)(row - 128) << 7) + (kb >> 1));
        *(ushort8_t*)((char*)sW + row * 256 + swz) = *(const ushort8_t*)gp;
    }

    // preload ALL A fragments (16 x 16B) — issues alongside W staging
    bf16x8_t a[2][2][4];
#pragma unroll
    for (int mat = 0; mat < 2; ++mat) {
        const ushort_t* As = mat ? Ab : Xb;
#pragma unroll
        for (int ks = 0; ks < 4; ++ks) {
            const int ko = ks * 32 + g * 8;
            a[mat][0][ks] = *(const bf16x8_t*)(As + (size_t)r0 * DF + ko);
            a[mat][1][ks] = *(const bf16x8_t*)(As + (size_t)r1 * DF + ko);
        }
    }

    __syncthreads();

    f32x4_t acc[2][8];
#pragma unroll
    for (int rf = 0; rf < 2; ++rf)
#pragma unroll
        for (int c = 0; c < 8; ++c) acc[rf][c] = (f32x4_t){0.f, 0.f, 0.f, 0.f};

#pragma unroll
    for (int mat = 0; mat < 2; ++mat) {
#pragma unroll
        for (int ks = 0; ks < 4; ++ks) {
            const int kb = ks * 64 + g * 16;  // byte offset within 256B row
#pragma unroll
            for (int c = 0; c < 8; ++c) {
                int brow = mat * 128 + c * 16 + l15;
                bf16x8_t b = *(const bf16x8_t*)((const char*)sW + brow * 256 +
                                                (kb ^ ((brow & 7) << 4)));
                acc[0][c] = __builtin_amdgcn_mfma_f32_16x16x32_bf16(a[mat][0][ks], b, acc[0][c], 0, 0, 0);
                acc[1][c] = __builtin_amdgcn_mfma_f32_16x16x32_bf16(a[mat][1][ks], b, acc[1][c], 0, 0, 0);
            }
        }
    }

    if (m0 + 32 <= M) {   // fast path: no per-store bounds checks
#pragma unroll
        for (int c = 0; c < 8; ++c) {
            int col = c * 16 + l15;
            float bv = bias[col];
#pragma unroll
            for (int rf = 0; rf < 2; ++rf)
#pragma unroll
                for (int j = 0; j < 4; ++j) {
                    int row = m0 + rf * 16 + g * 4 + j;
                    float v = fmaxf(acc[rf][c][j] + bv, 0.f);
                    if (BF16OUT) ((ushort_t*)outv)[(size_t)row * DF + col] = f2bf(v);
                    else         ((float*)outv)[(size_t)row * DF + col] = v;
                }
        }
    } else {
#pragma unroll
        for (int c = 0; c < 8; ++c) {
            int col = c * 16 + l15;
            float bv = bias[col];
#pragma unroll
            for (int rf = 0; rf < 2; ++rf)
#pragma unroll
                for (int j = 0; j < 4; ++j) {
                    int row = m0 + rf * 16 + g * 4 + j;
                    if (row < M) {
                        float v = fmaxf(acc[rf][c][j] + bv, 0.f);
                        if (BF16OUT) ((ushort_t*)outv)[(size_t)row * DF + col] = f2bf(v);
                        else         ((float*)outv)[(size_t)row * DF + col] = v;
                    }
                }
        }
    }
}

extern "C" void kernel_launch(void* const* d_in, const int* in_sizes, int n_in,
                              void* d_out, int out_size, void* d_ws, size_t ws_size,
                              hipStream_t stream) {
    const int N = in_sizes[0] / DF;   // 100000
    const int E = in_sizes[1];        // 1600000

    const float* x   = (const float*)d_in[0];
    const int*   src = (const int*)d_in[1];
    const int*   dst = (const int*)d_in[2];
    const float* Ws1 = (const float*)d_in[3];
    const float* Wn1 = (const float*)d_in[4];
    const float* b1  = (const float*)d_in[5];
    const float* Ws2 = (const float*)d_in[6];
    const float* Wn2 = (const float*)d_in[7];
    const float* b2  = (const float*)d_in[8];
    float* out = (float*)d_out;

    const int NBKT = (N + 255) >> 8;
    int CH = 4096;
    int NCH = (E + CH - 1) / CH;
    while (NCH > 512) { CH <<= 1; NCH = (E + CH - 1) / CH; }

    // workspace layout (~58.7 MB)
    int* rowptr   = (int*)d_ws;                                  // N+1
    int* rowbase  = rowptr + ((N + 1 + 63) & ~63);               // NBKT+1
    int* rowtot   = rowbase + ((NBKT + 1 + 63) & ~63);           // NBKT
    int* C        = rowtot + ((NBKT + 63) & ~63);                // NBKT*NCH
    ushort_t* Wt  = (ushort_t*)(C + ((NBKT * NCH + 63) & ~63));  // 4*16384 bf16
    int* edge_src = (int*)(Wt + 65536);                          // E
    ushort_t* Xb  = (ushort_t*)(edge_src + ((E + 63) & ~63));    // N*128 bf16
    ushort_t* Ab  = Xb + (size_t)N * DF;                         // N*128 bf16
    unsigned int* inter = (unsigned int*)Ab;                     // E u32 (dead before Ab use)

    conv_bf16_kernel<<<(N * DF / 8 + 255) / 256, 256, 0, stream>>>(x, Xb, N * DF / 8);
    k1_coarse_hist<<<NCH, 256, 0, stream>>>(dst, C, E, CH, NCH, NBKT);
    k2a_row_scan<<<NBKT, 512, 0, stream>>>(C, rowtot, NCH);
    k2b_base_scan<<<1, 512, 0, stream>>>(rowtot, rowbase, rowptr, NBKT, N, E);
    k3_bin_scatter<<<NCH, 256, 0, stream>>>(src, dst, C, rowbase, inter, E, CH, NCH, NBKT);
    k4_fine_scatter<<<NBKT, 256, 0, stream>>>(inter, rowbase, edge_src, rowptr, N);
    transpose_w_kernel<<<256, 256, 0, stream>>>(Ws1, Wn1, Ws2, Wn2, Wt);

    const int aggGrid  = (N + 3) / 4;
    const int gemmGrid = (N + 127) / 128;

    // layer 1: agg(Xb) -> Ab ; h1 = relu(Xb@Ws1 + Ab@Wn1 + b1) bf16 in-place over Xb
    aggregate_bf16_kernel<<<aggGrid, 256, 0, stream>>>(Xb, rowptr, edge_src, Ab, N);
    sage_mfma_kernel<1><<<gemmGrid, 256, 0, stream>>>(Xb, Ab, Wt, Wt + 16384, b1, (void*)Xb, N);
    // layer 2: agg(h1) -> Ab ; out = relu(h1@Ws2 + Ab@Wn2 + b2) fp32 to d_out
    aggregate_bf16_kernel<<<aggGrid, 256, 0, stream>>>(Xb, rowptr, edge_src, Ab, N);
    sage_mfma_kernel<0><<<gemmGrid, 256, 0, stream>>>(Xb, Ab, Wt + 32768, Wt + 49152, b2, (void*)out, N);
}

// Round 8
// 217.437 us; speedup vs baseline: 3.9004x; 1.0078x over previous
//
#include <hip/hip_runtime.h>

#define DF 128

typedef __bf16 bf16x8_t __attribute__((ext_vector_type(8)));
typedef float f32x4_t __attribute__((ext_vector_type(4)));
typedef unsigned short ushort_t;
typedef ushort_t ushort8_t __attribute__((ext_vector_type(8)));

static __device__ __forceinline__ ushort_t f2bf(float f) {
    union { float f; unsigned int u; } v; v.f = f;
    unsigned int r = v.u + 0x7fffu + ((v.u >> 16) & 1u);   // RNE
    return (ushort_t)(r >> 16);
}
static __device__ __forceinline__ float bflo(unsigned int v) {
    union { unsigned int u; float f; } c; c.u = v << 16; return c.f;
}
static __device__ __forceinline__ float bfhi(unsigned int v) {
    union { unsigned int u; float f; } c; c.u = v & 0xffff0000u; return c.f;
}

// ================= counting-sort CSR build (no global atomics) =================
// bucket = dst >> 8 (256 nodes/bucket). All random access stays in LDS.

__global__ __launch_bounds__(256) void k1_coarse_hist(
    const int* __restrict__ dst, int* __restrict__ C,
    int E, int CH, int NCH, int NBKT) {
    __shared__ int lcnt[512];
    const int c = blockIdx.x;
    for (int b = threadIdx.x; b < NBKT; b += 256) lcnt[b] = 0;
    __syncthreads();
    const int base = c * CH, lim = min(base + CH, E);
    for (int i = base + threadIdx.x; i < lim; i += 256)
        atomicAdd(&lcnt[dst[i] >> 8], 1);
    __syncthreads();
    for (int b = threadIdx.x; b < NBKT; b += 256) C[b * NCH + c] = lcnt[b];
}

__global__ __launch_bounds__(512) void k2a_row_scan(
    int* __restrict__ C, int* __restrict__ rowtot, int NCH) {
    __shared__ int sd[512];
    const int b = blockIdx.x, t = threadIdx.x;
    int v = (t < NCH) ? C[b * NCH + t] : 0;
    sd[t] = v; __syncthreads();
    for (int off = 1; off < 512; off <<= 1) {
        int u = (t >= off) ? sd[t - off] : 0;
        __syncthreads();
        sd[t] += u;
        __syncthreads();
    }
    if (t < NCH) C[b * NCH + t] = sd[t] - v;   // exclusive within row
    if (t == 511) rowtot[b] = sd[511];
}

__global__ __launch_bounds__(512) void k2b_base_scan(
    const int* __restrict__ rowtot, int* __restrict__ rowbase,
    int* __restrict__ rowptr, int NBKT, int N, int E) {
    __shared__ int sd[512];
    const int t = threadIdx.x;
    int v = (t < NBKT) ? rowtot[t] : 0;
    sd[t] = v; __syncthreads();
    for (int off = 1; off < 512; off <<= 1) {
        int u = (t >= off) ? sd[t - off] : 0;
        __syncthreads();
        sd[t] += u;
        __syncthreads();
    }
    if (t < NBKT) rowbase[t] = sd[t] - v;
    if (t == 0) { rowbase[NBKT] = E; rowptr[N] = E; }
}

__global__ __launch_bounds__(256) void k3_bin_scatter(
    const int* __restrict__ src, const int* __restrict__ dst,
    const int* __restrict__ C, const int* __restrict__ rowbase,
    unsigned int* __restrict__ inter, int E, int CH, int NCH, int NBKT) {
    __shared__ int cur[512];
    const int c = blockIdx.x;
    for (int b = threadIdx.x; b < NBKT; b += 256)
        cur[b] = rowbase[b] + C[b * NCH + c];
    __syncthreads();
    const int base = c * CH, lim = min(base + CH, E);
    for (int i = base + threadIdx.x; i < lim; i += 256) {
        int d = dst[i];
        int s = src[i];
        int pos = atomicAdd(&cur[d >> 8], 1);
        inter[pos] = ((unsigned int)(d & 255) << 24) | (unsigned int)s;
    }
}

#define K4CAP 6144
__global__ __launch_bounds__(256) void k4_fine_scatter(
    const unsigned int* __restrict__ inter, const int* __restrict__ rowbase,
    int* __restrict__ edge_src, int* __restrict__ rowptr, int N) {
    __shared__ unsigned int stage[K4CAP];
    __shared__ unsigned int outv[K4CAP];
    __shared__ int lcnt[256], lofs[256], lrun[256];
    const int b = blockIdx.x, t = threadIdx.x;
    const int base = rowbase[b], count = rowbase[b + 1] - base;
    const int n0 = b << 8;
    const int nn = min(256, N - n0);

    lcnt[t] = 0; lrun[t] = 0;
    __syncthreads();

    if (count <= K4CAP) {
        for (int i = t; i < count; i += 256) {
            unsigned int v = inter[base + i];
            stage[i] = v;
            atomicAdd(&lcnt[v >> 24], 1);
        }
        __syncthreads();
        int cv = lcnt[t];
        lofs[t] = cv; __syncthreads();
        for (int off = 1; off < 256; off <<= 1) {
            int u = (t >= off) ? lofs[t - off] : 0;
            __syncthreads();
            lofs[t] += u;
            __syncthreads();
        }
        lofs[t] -= cv;   // exclusive
        if (t < nn) rowptr[n0 + t] = base + lofs[t];
        __syncthreads();
        for (int i = t; i < count; i += 256) {
            unsigned int v = stage[i];
            int dl = v >> 24;
            int p = lofs[dl] + atomicAdd(&lrun[dl], 1);
            outv[p] = v & 0xFFFFFFu;
        }
        __syncthreads();
        for (int i = t; i < count; i += 256) edge_src[base + i] = (int)outv[i];
    } else {
        for (int i = t; i < count; i += 256)
            atomicAdd(&lcnt[inter[base + i] >> 24], 1);
        __syncthreads();
        int cv = lcnt[t];
        lofs[t] = cv; __syncthreads();
        for (int off = 1; off < 256; off <<= 1) {
            int u = (t >= off) ? lofs[t - off] : 0;
            __syncthreads();
            lofs[t] += u;
            __syncthreads();
        }
        lofs[t] -= cv;
        if (t < nn) rowptr[n0 + t] = base + lofs[t];
        __syncthreads();
        for (int i = t; i < count; i += 256) {
            unsigned int v = inter[base + i];
            int dl = v >> 24;
            int p = atomicAdd(&lrun[dl], 1);
            edge_src[base + lofs[dl] + p] = (int)(v & 0xFFFFFFu);
        }
    }
}

// ---------------- x (fp32) -> bf16 ----------------
__global__ __launch_bounds__(256) void conv_bf16_kernel(const float* __restrict__ in,
                                                        ushort_t* __restrict__ out, int n8) {
    int i = blockIdx.x * blockDim.x + threadIdx.x;
    if (i >= n8) return;
    float4 a = ((const float4*)in)[(size_t)i * 2];
    float4 b = ((const float4*)in)[(size_t)i * 2 + 1];
    ushort8_t o;
    o[0] = f2bf(a.x); o[1] = f2bf(a.y); o[2] = f2bf(a.z); o[3] = f2bf(a.w);
    o[4] = f2bf(b.x); o[5] = f2bf(b.y); o[6] = f2bf(b.z); o[7] = f2bf(b.w);
    ((ushort8_t*)out)[i] = o;
}

// ---------------- W (fp32 [k][n]) -> W^T (bf16 [n][k]), 4 matrices ----------------
__global__ void transpose_w_kernel(const float* __restrict__ W0, const float* __restrict__ W1,
                                   const float* __restrict__ W2, const float* __restrict__ W3,
                                   ushort_t* __restrict__ out) {
    int m = blockIdx.x >> 6;
    const float* W = (m == 0) ? W0 : (m == 1) ? W1 : (m == 2) ? W2 : W3;
    int idx = (blockIdx.x & 63) * 256 + threadIdx.x;
    int k = idx >> 7, n = idx & 127;
    out[m * 16384 + n * 128 + k] = f2bf(W[idx]);
}

// ---------------- mean aggregation: 1 wave/node, 4 edges/group in flight ----------------
// 4 groups x 16 lanes; each group issues 4 INDEPENDENT uint4 gathers per iter
// (16 edges/wave/iter, 4 KB in flight per wave) — R7 was MLP-bound at 2 loads.
// CROSS-LANE DISCIPLINE: shfl always executes with all 64 lanes active, clamped
// source lane; only loads/accumulation are predicated (R4 lesson).
__global__ __launch_bounds__(256, 4) void aggregate_bf16_kernel(
    const ushort_t* __restrict__ Xb, const int* __restrict__ rowptr,
    const int* __restrict__ edge_src, ushort_t* __restrict__ out, int N) {
    int node = (int)((blockIdx.x * 256u + threadIdx.x) >> 6);
    int lane = threadIdx.x & 63;
    if (node >= N) return;
    const int g = lane >> 4;
    const int s = lane & 15;
    int beg = rowptr[node], end = rowptr[node + 1];
    int deg = end - beg;
    float acc[8] = {0.f, 0.f, 0.f, 0.f, 0.f, 0.f, 0.f, 0.f};
    for (int b0 = 0; b0 < deg; b0 += 64) {
        int nb = min(64, deg - b0);
        int idx = (lane < nb) ? edge_src[beg + b0 + lane] : 0;
        int nfull = nb >> 4;                  // full 16-edge rounds (uniform)
        for (int it = 0; it < nfull; ++it) {
            int j = it * 16 + g * 4;          // group g owns edges j..j+3
            int s0 = __shfl(idx, j, 64);
            int s1 = __shfl(idx, j + 1, 64);
            int s2 = __shfl(idx, j + 2, 64);
            int s3 = __shfl(idx, j + 3, 64);
            uint4 v0 = *(const uint4*)(Xb + (size_t)s0 * DF + s * 8);
            uint4 v1 = *(const uint4*)(Xb + (size_t)s1 * DF + s * 8);
            uint4 v2 = *(const uint4*)(Xb + (size_t)s2 * DF + s * 8);
            uint4 v3 = *(const uint4*)(Xb + (size_t)s3 * DF + s * 8);
            acc[0] += (bflo(v0.x) + bflo(v1.x)) + (bflo(v2.x) + bflo(v3.x));
            acc[1] += (bfhi(v0.x) + bfhi(v1.x)) + (bfhi(v2.x) + bfhi(v3.x));
            acc[2] += (bflo(v0.y) + bflo(v1.y)) + (bflo(v2.y) + bflo(v3.y));
            acc[3] += (bfhi(v0.y) + bfhi(v1.y)) + (bfhi(v2.y) + bfhi(v3.y));
            acc[4] += (bflo(v0.z) + bflo(v1.z)) + (bflo(v2.z) + bflo(v3.z));
            acc[5] += (bfhi(v0.z) + bfhi(v1.z)) + (bfhi(v2.z) + bfhi(v3.z));
            acc[6] += (bflo(v0.w) + bflo(v1.w)) + (bflo(v2.w) + bflo(v3.w));
            acc[7] += (bfhi(v0.w) + bfhi(v1.w)) + (bfhi(v2.w) + bfhi(v3.w));
        }
        if (nb & 15) {   // one wave-uniform predicated tail round (<=15 edges)
            int j = nfull * 16 + g * 4;
            int j0 = j, j1 = j + 1, j2 = j + 2, j3 = j + 3;
            int s0 = __shfl(idx, (j0 < nb) ? j0 : 0, 64);   // full wave active
            int s1 = __shfl(idx, (j1 < nb) ? j1 : 0, 64);
            int s2 = __shfl(idx, (j2 < nb) ? j2 : 0, 64);
            int s3 = __shfl(idx, (j3 < nb) ? j3 : 0, 64);
            uint4 z = make_uint4(0, 0, 0, 0);
            uint4 v0 = z, v1 = z, v2 = z, v3 = z;
            if (j0 < nb) v0 = *(const uint4*)(Xb + (size_t)s0 * DF + s * 8);
            if (j1 < nb) v1 = *(const uint4*)(Xb + (size_t)s1 * DF + s * 8);
            if (j2 < nb) v2 = *(const uint4*)(Xb + (size_t)s2 * DF + s * 8);
            if (j3 < nb) v3 = *(const uint4*)(Xb + (size_t)s3 * DF + s * 8);
            acc[0] += (bflo(v0.x) + bflo(v1.x)) + (bflo(v2.x) + bflo(v3.x));
            acc[1] += (bfhi(v0.x) + bfhi(v1.x)) + (bfhi(v2.x) + bfhi(v3.x));
            acc[2] += (bflo(v0.y) + bflo(v1.y)) + (bflo(v2.y) + bflo(v3.y));
            acc[3] += (bfhi(v0.y) + bfhi(v1.y)) + (bfhi(v2.y) + bfhi(v3.y));
            acc[4] += (bflo(v0.z) + bflo(v1.z)) + (bflo(v2.z) + bflo(v3.z));
            acc[5] += (bfhi(v0.z) + bfhi(v1.z)) + (bfhi(v2.z) + bfhi(v3.z));
            acc[6] += (bflo(v0.w) + bflo(v1.w)) + (bflo(v2.w) + bflo(v3.w));
            acc[7] += (bfhi(v0.w) + bfhi(v1.w)) + (bfhi(v2.w) + bfhi(v3.w));
        }
    }
#pragma unroll
    for (int i = 0; i < 8; ++i) {
        acc[i] += __shfl_xor(acc[i], 16, 64);
        acc[i] += __shfl_xor(acc[i], 32, 64);
    }
    if (g == 0) {
        float inv = 1.0f / fmaxf((float)deg, 1.0f);
        ushort8_t o;
#pragma unroll
        for (int i = 0; i < 8; ++i) o[i] = f2bf(acc[i] * inv);
        *(ushort8_t*)(out + (size_t)node * DF + s * 8) = o;
    }
}

// ---------------- fused SAGE GEMM via MFMA, W^T in swizzled LDS ----------------
// out = relu(Xb@Ws^T' + Ab@Wn^T' + b). ALL 16 A-fragments preloaded to registers
// before the W barrier. Xb may alias out (in-place): reads precede stores.
template <int BF16OUT>
__global__ __launch_bounds__(256, 2) void sage_mfma_kernel(
    const ushort_t* Xb, const ushort_t* __restrict__ Ab,
    const ushort_t* __restrict__ Wts, const ushort_t* __restrict__ Wtn,
    const float* __restrict__ bias, void* outv, int M) {
    __shared__ ushort_t sW[32768];   // 64 KB: [mat(2)][row(128)][k(128)] bf16, swizzled

    const int lane = threadIdx.x & 63;
    const int w = threadIdx.x >> 6;
    const int l15 = lane & 15;
    const int g = lane >> 4;
    const int m0 = blockIdx.x * 128 + w * 32;

    int r0 = m0 + l15;      if (r0 >= M) r0 = M - 1;
    int r1 = m0 + 16 + l15; if (r1 >= M) r1 = M - 1;

    // stage both W^T matrices into LDS (swizzle on write: byte ^= (row&7)<<4)
    for (int u = threadIdx.x; u < 4096; u += 256) {
        int row = u >> 4;
        int kb  = (u & 15) << 4;
        int swz = kb ^ ((row & 7) << 4);
        const ushort_t* gp = (row < 128)
            ? (Wts + ((size_t)row << 7) + (kb >> 1))
            : (Wtn + ((size_t)(row - 128) << 7) + (kb >> 1));
        *(ushort8_t*)((char*)sW + row * 256 + swz) = *(const ushort8_t*)gp;
    }

    // preload ALL A fragments (16 x 16B) — issues alongside W staging
    bf16x8_t a[2][2][4];
#pragma unroll
    for (int mat = 0; mat < 2; ++mat) {
        const ushort_t* As = mat ? Ab : Xb;
#pragma unroll
        for (int ks = 0; ks < 4; ++ks) {
            const int ko = ks * 32 + g * 8;
            a[mat][0][ks] = *(const bf16x8_t*)(As + (size_t)r0 * DF + ko);
            a[mat][1][ks] = *(const bf16x8_t*)(As + (size_t)r1 * DF + ko);
        }
    }

    __syncthreads();

    f32x4_t acc[2][8];
#pragma unroll
    for (int rf = 0; rf < 2; ++rf)
#pragma unroll
        for (int c = 0; c < 8; ++c) acc[rf][c] = (f32x4_t){0.f, 0.f, 0.f, 0.f};

#pragma unroll
    for (int mat = 0; mat < 2; ++mat) {
#pragma unroll
        for (int ks = 0; ks < 4; ++ks) {
            const int kb = ks * 64 + g * 16;  // byte offset within 256B row
#pragma unroll
            for (int c = 0; c < 8; ++c) {
                int brow = mat * 128 + c * 16 + l15;
                bf16x8_t b = *(const bf16x8_t*)((const char*)sW + brow * 256 +
                                                (kb ^ ((brow & 7) << 4)));
                acc[0][c] = __builtin_amdgcn_mfma_f32_16x16x32_bf16(a[mat][0][ks], b, acc[0][c], 0, 0, 0);
                acc[1][c] = __builtin_amdgcn_mfma_f32_16x16x32_bf16(a[mat][1][ks], b, acc[1][c], 0, 0, 0);
            }
        }
    }

    if (m0 + 32 <= M) {   // fast path: no per-store bounds checks
#pragma unroll
        for (int c = 0; c < 8; ++c) {
            int col = c * 16 + l15;
            float bv = bias[col];
#pragma unroll
            for (int rf = 0; rf < 2; ++rf)
#pragma unroll
                for (int j = 0; j < 4; ++j) {
                    int row = m0 + rf * 16 + g * 4 + j;
                    float v = fmaxf(acc[rf][c][j] + bv, 0.f);
                    if (BF16OUT) ((ushort_t*)outv)[(size_t)row * DF + col] = f2bf(v);
                    else         ((float*)outv)[(size_t)row * DF + col] = v;
                }
        }
    } else {
#pragma unroll
        for (int c = 0; c < 8; ++c) {
            int col = c * 16 + l15;
            float bv = bias[col];
#pragma unroll
            for (int rf = 0; rf < 2; ++rf)
#pragma unroll
                for (int j = 0; j < 4; ++j) {
                    int row = m0 + rf * 16 + g * 4 + j;
                    if (row < M) {
                        float v = fmaxf(acc[rf][c][j] + bv, 0.f);
                        if (BF16OUT) ((ushort_t*)outv)[(size_t)row * DF + col] = f2bf(v);
                        else         ((float*)outv)[(size_t)row * DF + col] = v;
                    }
                }
        }
    }
}

extern "C" void kernel_launch(void* const* d_in, const int* in_sizes, int n_in,
                              void* d_out, int out_size, void* d_ws, size_t ws_size,
                              hipStream_t stream) {
    const int N = in_sizes[0] / DF;   // 100000
    const int E = in_sizes[1];        // 1600000

    const float* x   = (const float*)d_in[0];
    const int*   src = (const int*)d_in[1];
    const int*   dst = (const int*)d_in[2];
    const float* Ws1 = (const float*)d_in[3];
    const float* Wn1 = (const float*)d_in[4];
    const float* b1  = (const float*)d_in[5];
    const float* Ws2 = (const float*)d_in[6];
    const float* Wn2 = (const float*)d_in[7];
    const float* b2  = (const float*)d_in[8];
    float* out = (float*)d_out;

    const int NBKT = (N + 255) >> 8;
    int CH = 4096;
    int NCH = (E + CH - 1) / CH;
    while (NCH > 512) { CH <<= 1; NCH = (E + CH - 1) / CH; }

    // workspace layout (~58.7 MB)
    int* rowptr   = (int*)d_ws;                                  // N+1
    int* rowbase  = rowptr + ((N + 1 + 63) & ~63);               // NBKT+1
    int* rowtot   = rowbase + ((NBKT + 1 + 63) & ~63);           // NBKT
    int* C        = rowtot + ((NBKT + 63) & ~63);                // NBKT*NCH
    ushort_t* Wt  = (ushort_t*)(C + ((NBKT * NCH + 63) & ~63));  // 4*16384 bf16
    int* edge_src = (int*)(Wt + 65536);                          // E
    ushort_t* Xb  = (ushort_t*)(edge_src + ((E + 63) & ~63));    // N*128 bf16
    ushort_t* Ab  = Xb + (size_t)N * DF;                         // N*128 bf16
    unsigned int* inter = (unsigned int*)Ab;                     // E u32 (dead before Ab use)

    conv_bf16_kernel<<<(N * DF / 8 + 255) / 256, 256, 0, stream>>>(x, Xb, N * DF / 8);
    k1_coarse_hist<<<NCH, 256, 0, stream>>>(dst, C, E, CH, NCH, NBKT);
    k2a_row_scan<<<NBKT, 512, 0, stream>>>(C, rowtot, NCH);
    k2b_base_scan<<<1, 512, 0, stream>>>(rowtot, rowbase, rowptr, NBKT, N, E);
    k3_bin_scatter<<<NCH, 256, 0, stream>>>(src, dst, C, rowbase, inter, E, CH, NCH, NBKT);
    k4_fine_scatter<<<NBKT, 256, 0, stream>>>(inter, rowbase, edge_src, rowptr, N);
    transpose_w_kernel<<<256, 256, 0, stream>>>(Ws1, Wn1, Ws2, Wn2, Wt);

    const int aggGrid  = (N + 3) / 4;
    const int gemmGrid = (N + 127) / 128;

    // layer 1: agg(Xb) -> Ab ; h1 = relu(Xb@Ws1 + Ab@Wn1 + b1) bf16 in-place over Xb
    aggregate_bf16_kernel<<<aggGrid, 256, 0, stream>>>(Xb, rowptr, edge_src, Ab, N);
    sage_mfma_kernel<1><<<gemmGrid, 256, 0, stream>>>(Xb, Ab, Wt, Wt + 16384, b1, (void*)Xb, N);
    // layer 2: agg(h1) -> Ab ; out = relu(h1@Ws2 + Ab@Wn2 + b2) fp32 to d_out
    aggregate_bf16_kernel<<<aggGrid, 256, 0, stream>>>(Xb, rowptr, edge_src, Ab, N);
    sage_mfma_kernel<0><<<gemmGrid, 256, 0, stream>>>(Xb, Ab, Wt + 32768, Wt + 49152, b2, (void*)out, N);
}

// Round 9
// 196.730 us; speedup vs baseline: 4.3110x; 1.1053x over previous
//
#include <hip/hip_runtime.h>

#define DF 128

typedef __bf16 bf16x8_t __attribute__((ext_vector_type(8)));
typedef float f32x4_t __attribute__((ext_vector_type(4)));
typedef float f32x2_t __attribute__((ext_vector_type(2)));
typedef unsigned short ushort_t;
typedef ushort_t ushort8_t __attribute__((ext_vector_type(8)));

static __device__ __forceinline__ ushort_t f2bf(float f) {
    union { float f; unsigned int u; } v; v.f = f;
    unsigned int r = v.u + 0x7fffu + ((v.u >> 16) & 1u);   // RNE
    return (ushort_t)(r >> 16);
}
static __device__ __forceinline__ float bf2f(ushort_t v) {
    union { unsigned int u; float f; } c; c.u = ((unsigned int)v) << 16; return c.f;
}

// ================= counting-sort CSR build (no global atomics) =================
__global__ __launch_bounds__(256) void k1_coarse_hist(
    const int* __restrict__ dst, int* __restrict__ C,
    int E, int CH, int NCH, int NBKT) {
    __shared__ int lcnt[512];
    const int c = blockIdx.x;
    for (int b = threadIdx.x; b < NBKT; b += 256) lcnt[b] = 0;
    __syncthreads();
    const int base = c * CH, lim = min(base + CH, E);
    for (int i = base + threadIdx.x; i < lim; i += 256)
        atomicAdd(&lcnt[dst[i] >> 8], 1);
    __syncthreads();
    for (int b = threadIdx.x; b < NBKT; b += 256) C[b * NCH + c] = lcnt[b];
}

__global__ __launch_bounds__(512) void k2a_row_scan(
    int* __restrict__ C, int* __restrict__ rowtot, int NCH) {
    __shared__ int sd[512];
    const int b = blockIdx.x, t = threadIdx.x;
    int v = (t < NCH) ? C[b * NCH + t] : 0;
    sd[t] = v; __syncthreads();
    for (int off = 1; off < 512; off <<= 1) {
        int u = (t >= off) ? sd[t - off] : 0;
        __syncthreads();
        sd[t] += u;
        __syncthreads();
    }
    if (t < NCH) C[b * NCH + t] = sd[t] - v;
    if (t == 511) rowtot[b] = sd[511];
}

__global__ __launch_bounds__(512) void k2b_base_scan(
    const int* __restrict__ rowtot, int* __restrict__ rowbase,
    int* __restrict__ rowptr, int NBKT, int N, int E) {
    __shared__ int sd[512];
    const int t = threadIdx.x;
    int v = (t < NBKT) ? rowtot[t] : 0;
    sd[t] = v; __syncthreads();
    for (int off = 1; off < 512; off <<= 1) {
        int u = (t >= off) ? sd[t - off] : 0;
        __syncthreads();
        sd[t] += u;
        __syncthreads();
    }
    if (t < NBKT) rowbase[t] = sd[t] - v;
    if (t == 0) { rowbase[NBKT] = E; rowptr[N] = E; }
}

__global__ __launch_bounds__(256) void k3_bin_scatter(
    const int* __restrict__ src, const int* __restrict__ dst,
    const int* __restrict__ C, const int* __restrict__ rowbase,
    unsigned int* __restrict__ inter, int E, int CH, int NCH, int NBKT) {
    __shared__ int cur[512];
    const int c = blockIdx.x;
    for (int b = threadIdx.x; b < NBKT; b += 256)
        cur[b] = rowbase[b] + C[b * NCH + c];
    __syncthreads();
    const int base = c * CH, lim = min(base + CH, E);
    for (int i = base + threadIdx.x; i < lim; i += 256) {
        int d = dst[i];
        int s = src[i];
        int pos = atomicAdd(&cur[d >> 8], 1);
        inter[pos] = ((unsigned int)(d & 255) << 24) | (unsigned int)s;
    }
}

#define K4CAP 6144
__global__ __launch_bounds__(256) void k4_fine_scatter(
    const unsigned int* __restrict__ inter, const int* __restrict__ rowbase,
    int* __restrict__ edge_src, int* __restrict__ rowptr, int N) {
    __shared__ unsigned int stage[K4CAP];
    __shared__ unsigned int outv[K4CAP];
    __shared__ int lcnt[256], lofs[256], lrun[256];
    const int b = blockIdx.x, t = threadIdx.x;
    const int base = rowbase[b], count = rowbase[b + 1] - base;
    const int n0 = b << 8;
    const int nn = min(256, N - n0);

    lcnt[t] = 0; lrun[t] = 0;
    __syncthreads();

    if (count <= K4CAP) {
        for (int i = t; i < count; i += 256) {
            unsigned int v = inter[base + i];
            stage[i] = v;
            atomicAdd(&lcnt[v >> 24], 1);
        }
        __syncthreads();
        int cv = lcnt[t];
        lofs[t] = cv; __syncthreads();
        for (int off = 1; off < 256; off <<= 1) {
            int u = (t >= off) ? lofs[t - off] : 0;
            __syncthreads();
            lofs[t] += u;
            __syncthreads();
        }
        lofs[t] -= cv;
        if (t < nn) rowptr[n0 + t] = base + lofs[t];
        __syncthreads();
        for (int i = t; i < count; i += 256) {
            unsigned int v = stage[i];
            int dl = v >> 24;
            int p = lofs[dl] + atomicAdd(&lrun[dl], 1);
            outv[p] = v & 0xFFFFFFu;
        }
        __syncthreads();
        for (int i = t; i < count; i += 256) edge_src[base + i] = (int)outv[i];
    } else {
        for (int i = t; i < count; i += 256)
            atomicAdd(&lcnt[inter[base + i] >> 24], 1);
        __syncthreads();
        int cv = lcnt[t];
        lofs[t] = cv; __syncthreads();
        for (int off = 1; off < 256; off <<= 1) {
            int u = (t >= off) ? lofs[t - off] : 0;
            __syncthreads();
            lofs[t] += u;
            __syncthreads();
        }
        lofs[t] -= cv;
        if (t < nn) rowptr[n0 + t] = base + lofs[t];
        __syncthreads();
        for (int i = t; i < count; i += 256) {
            unsigned int v = inter[base + i];
            int dl = v >> 24;
            int p = atomicAdd(&lrun[dl], 1);
            edge_src[base + lofs[dl] + p] = (int)(v & 0xFFFFFFu);
        }
    }
}

// ---------------- x (fp32) -> bf16 + fp8(e4m3) in one pass ----------------
__global__ __launch_bounds__(256) void conv_dual_kernel(
    const float* __restrict__ in, ushort_t* __restrict__ outb,
    unsigned char* __restrict__ out8, int n8) {
    int i = blockIdx.x * blockDim.x + threadIdx.x;
    if (i >= n8) return;
    float4 a = ((const float4*)in)[(size_t)i * 2];
    float4 b = ((const float4*)in)[(size_t)i * 2 + 1];
    ushort8_t o;
    o[0] = f2bf(a.x); o[1] = f2bf(a.y); o[2] = f2bf(a.z); o[3] = f2bf(a.w);
    o[4] = f2bf(b.x); o[5] = f2bf(b.y); o[6] = f2bf(b.z); o[7] = f2bf(b.w);
    ((ushort8_t*)outb)[i] = o;
    int lo = __builtin_amdgcn_cvt_pk_fp8_f32(a.x, a.y, 0, false);
    lo     = __builtin_amdgcn_cvt_pk_fp8_f32(a.z, a.w, lo, true);
    int hi = __builtin_amdgcn_cvt_pk_fp8_f32(b.x, b.y, 0, false);
    hi     = __builtin_amdgcn_cvt_pk_fp8_f32(b.z, b.w, hi, true);
    ((uint2*)out8)[i] = make_uint2((unsigned int)lo, (unsigned int)hi);
}

// ---------------- h1 (bf16) -> fp8(e4m3) ----------------
__global__ __launch_bounds__(256) void conv_b2f8_kernel(
    const ushort_t* __restrict__ in, unsigned char* __restrict__ out8, int n8) {
    int i = blockIdx.x * blockDim.x + threadIdx.x;
    if (i >= n8) return;
    ushort8_t v = ((const ushort8_t*)in)[i];
    int lo = __builtin_amdgcn_cvt_pk_fp8_f32(bf2f(v[0]), bf2f(v[1]), 0, false);
    lo     = __builtin_amdgcn_cvt_pk_fp8_f32(bf2f(v[2]), bf2f(v[3]), lo, true);
    int hi = __builtin_amdgcn_cvt_pk_fp8_f32(bf2f(v[4]), bf2f(v[5]), 0, false);
    hi     = __builtin_amdgcn_cvt_pk_fp8_f32(bf2f(v[6]), bf2f(v[7]), hi, true);
    ((uint2*)out8)[i] = make_uint2((unsigned int)lo, (unsigned int)hi);
}

// ---------------- W (fp32 [k][n]) -> W^T (bf16 [n][k]), 4 matrices ----------------
__global__ void transpose_w_kernel(const float* __restrict__ W0, const float* __restrict__ W1,
                                   const float* __restrict__ W2, const float* __restrict__ W3,
                                   ushort_t* __restrict__ out) {
    int m = blockIdx.x >> 6;
    const float* W = (m == 0) ? W0 : (m == 1) ? W1 : (m == 2) ? W2 : W3;
    int idx = (blockIdx.x & 63) * 256 + threadIdx.x;
    int k = idx >> 7, n = idx & 127;
    out[m * 16384 + n * 128 + k] = f2bf(W[idx]);
}

// ---------------- mean aggregation over fp8 rows: 1 wave/node ----------------
// Row = 128 B (fp8): 2 cache lines/edge (bf16 was 4 — attacks the per-CU
// line-throughput floor R8 exposed). Unpack via v_cvt_pk_f32_fp8 (2 elems/op)
// + packed f32x2 adds: ~1 VALU/element (bf16 path was 2).
// CROSS-LANE DISCIPLINE: shfl always full-wave, clamped source (R4 lesson).
__global__ __launch_bounds__(256, 4) void aggregate_fp8_kernel(
    const unsigned char* __restrict__ Xf8, const int* __restrict__ rowptr,
    const int* __restrict__ edge_src, ushort_t* __restrict__ out, int N) {
    int node = (int)((blockIdx.x * 256u + threadIdx.x) >> 6);
    int lane = threadIdx.x & 63;
    if (node >= N) return;
    const int g = lane >> 4;
    const int s = lane & 15;
    int beg = rowptr[node], end = rowptr[node + 1];
    int deg = end - beg;
    f32x2_t ac0 = {0.f, 0.f}, ac1 = {0.f, 0.f}, ac2 = {0.f, 0.f}, ac3 = {0.f, 0.f};
    for (int b0 = 0; b0 < deg; b0 += 64) {
        int nb = min(64, deg - b0);
        int idx = (lane < nb) ? edge_src[beg + b0 + lane] : 0;
        int nfull = nb >> 4;                  // full 16-edge rounds (uniform)
        for (int it = 0; it < nfull; ++it) {
            int j = it * 16 + g * 4;          // group g owns edges j..j+3
            int s0 = __shfl(idx, j, 64);
            int s1 = __shfl(idx, j + 1, 64);
            int s2 = __shfl(idx, j + 2, 64);
            int s3 = __shfl(idx, j + 3, 64);
            uint2 v0 = *(const uint2*)(Xf8 + (size_t)s0 * DF + s * 8);
            uint2 v1 = *(const uint2*)(Xf8 + (size_t)s1 * DF + s * 8);
            uint2 v2 = *(const uint2*)(Xf8 + (size_t)s2 * DF + s * 8);
            uint2 v3 = *(const uint2*)(Xf8 + (size_t)s3 * DF + s * 8);
            ac0 += __builtin_amdgcn_cvt_pk_f32_fp8((int)v0.x, false);
            ac1 += __builtin_amdgcn_cvt_pk_f32_fp8((int)v0.x, true);
            ac2 += __builtin_amdgcn_cvt_pk_f32_fp8((int)v0.y, false);
            ac3 += __builtin_amdgcn_cvt_pk_f32_fp8((int)v0.y, true);
            ac0 += __builtin_amdgcn_cvt_pk_f32_fp8((int)v1.x, false);
            ac1 += __builtin_amdgcn_cvt_pk_f32_fp8((int)v1.x, true);
            ac2 += __builtin_amdgcn_cvt_pk_f32_fp8((int)v1.y, false);
            ac3 += __builtin_amdgcn_cvt_pk_f32_fp8((int)v1.y, true);
            ac0 += __builtin_amdgcn_cvt_pk_f32_fp8((int)v2.x, false);
            ac1 += __builtin_amdgcn_cvt_pk_f32_fp8((int)v2.x, true);
            ac2 += __builtin_amdgcn_cvt_pk_f32_fp8((int)v2.y, false);
            ac3 += __builtin_amdgcn_cvt_pk_f32_fp8((int)v2.y, true);
            ac0 += __builtin_amdgcn_cvt_pk_f32_fp8((int)v3.x, false);
            ac1 += __builtin_amdgcn_cvt_pk_f32_fp8((int)v3.x, true);
            ac2 += __builtin_amdgcn_cvt_pk_f32_fp8((int)v3.y, false);
            ac3 += __builtin_amdgcn_cvt_pk_f32_fp8((int)v3.y, true);
        }
        if (nb & 15) {   // one wave-uniform predicated tail round (<=15 edges)
            int j = nfull * 16 + g * 4;
            int j0 = j, j1 = j + 1, j2 = j + 2, j3 = j + 3;
            int s0 = __shfl(idx, (j0 < nb) ? j0 : 0, 64);   // full wave active
            int s1 = __shfl(idx, (j1 < nb) ? j1 : 0, 64);
            int s2 = __shfl(idx, (j2 < nb) ? j2 : 0, 64);
            int s3 = __shfl(idx, (j3 < nb) ? j3 : 0, 64);
            uint2 z = make_uint2(0, 0);      // fp8 0x00 == 0.0f
            uint2 v0 = z, v1 = z, v2 = z, v3 = z;
            if (j0 < nb) v0 = *(const uint2*)(Xf8 + (size_t)s0 * DF + s * 8);
            if (j1 < nb) v1 = *(const uint2*)(Xf8 + (size_t)s1 * DF + s * 8);
            if (j2 < nb) v2 = *(const uint2*)(Xf8 + (size_t)s2 * DF + s * 8);
            if (j3 < nb) v3 = *(const uint2*)(Xf8 + (size_t)s3 * DF + s * 8);
            ac0 += __builtin_amdgcn_cvt_pk_f32_fp8((int)v0.x, false);
            ac1 += __builtin_amdgcn_cvt_pk_f32_fp8((int)v0.x, true);
            ac2 += __builtin_amdgcn_cvt_pk_f32_fp8((int)v0.y, false);
            ac3 += __builtin_amdgcn_cvt_pk_f32_fp8((int)v0.y, true);
            ac0 += __builtin_amdgcn_cvt_pk_f32_fp8((int)v1.x, false);
            ac1 += __builtin_amdgcn_cvt_pk_f32_fp8((int)v1.x, true);
            ac2 += __builtin_amdgcn_cvt_pk_f32_fp8((int)v1.y, false);
            ac3 += __builtin_amdgcn_cvt_pk_f32_fp8((int)v1.y, true);
            ac0 += __builtin_amdgcn_cvt_pk_f32_fp8((int)v2.x, false);
            ac1 += __builtin_amdgcn_cvt_pk_f32_fp8((int)v2.x, true);
            ac2 += __builtin_amdgcn_cvt_pk_f32_fp8((int)v2.y, false);
            ac3 += __builtin_amdgcn_cvt_pk_f32_fp8((int)v2.y, true);
            ac0 += __builtin_amdgcn_cvt_pk_f32_fp8((int)v3.x, false);
            ac1 += __builtin_amdgcn_cvt_pk_f32_fp8((int)v3.x, true);
            ac2 += __builtin_amdgcn_cvt_pk_f32_fp8((int)v3.y, false);
            ac3 += __builtin_amdgcn_cvt_pk_f32_fp8((int)v3.y, true);
        }
    }
    float r[8] = {ac0[0], ac0[1], ac1[0], ac1[1], ac2[0], ac2[1], ac3[0], ac3[1]};
#pragma unroll
    for (int i = 0; i < 8; ++i) {
        r[i] += __shfl_xor(r[i], 16, 64);
        r[i] += __shfl_xor(r[i], 32, 64);
    }
    if (g == 0) {
        float inv = 1.0f / fmaxf((float)deg, 1.0f);
        ushort8_t o;
#pragma unroll
        for (int i = 0; i < 8; ++i) o[i] = f2bf(r[i] * inv);
        *(ushort8_t*)(out + (size_t)node * DF + s * 8) = o;
    }
}

// ---------------- fused SAGE GEMM via MFMA, W^T in swizzled LDS ----------------
// (unchanged from R8) out = relu(Xb@Ws^T' + Ab@Wn^T' + b).
template <int BF16OUT>
__global__ __launch_bounds__(256, 2) void sage_mfma_kernel(
    const ushort_t* Xb, const ushort_t* __restrict__ Ab,
    const ushort_t* __restrict__ Wts, const ushort_t* __restrict__ Wtn,
    const float* __restrict__ bias, void* outv, int M) {
    __shared__ ushort_t sW[32768];

    const int lane = threadIdx.x & 63;
    const int w = threadIdx.x >> 6;
    const int l15 = lane & 15;
    const int g = lane >> 4;
    const int m0 = blockIdx.x * 128 + w * 32;

    int r0 = m0 + l15;      if (r0 >= M) r0 = M - 1;
    int r1 = m0 + 16 + l15; if (r1 >= M) r1 = M - 1;

    for (int u = threadIdx.x; u < 4096; u += 256) {
        int row = u >> 4;
        int kb  = (u & 15) << 4;
        int swz = kb ^ ((row & 7) << 4);
        const ushort_t* gp = (row < 128)
            ? (Wts + ((size_t)row << 7) + (kb >> 1))
            : (Wtn + ((size_t)(row - 128) << 7) + (kb >> 1));
        *(ushort8_t*)((char*)sW + row * 256 + swz) = *(const ushort8_t*)gp;
    }

    bf16x8_t a[2][2][4];
#pragma unroll
    for (int mat = 0; mat < 2; ++mat) {
        const ushort_t* As = mat ? Ab : Xb;
#pragma unroll
        for (int ks = 0; ks < 4; ++ks) {
            const int ko = ks * 32 + g * 8;
            a[mat][0][ks] = *(const bf16x8_t*)(As + (size_t)r0 * DF + ko);
            a[mat][1][ks] = *(const bf16x8_t*)(As + (size_t)r1 * DF + ko);
        }
    }

    __syncthreads();

    f32x4_t acc[2][8];
#pragma unroll
    for (int rf = 0; rf < 2; ++rf)
#pragma unroll
        for (int c = 0; c < 8; ++c) acc[rf][c] = (f32x4_t){0.f, 0.f, 0.f, 0.f};

#pragma unroll
    for (int mat = 0; mat < 2; ++mat) {
#pragma unroll
        for (int ks = 0; ks < 4; ++ks) {
            const int kb = ks * 64 + g * 16;
#pragma unroll
            for (int c = 0; c < 8; ++c) {
                int brow = mat * 128 + c * 16 + l15;
                bf16x8_t b = *(const bf16x8_t*)((const char*)sW + brow * 256 +
                                                (kb ^ ((brow & 7) << 4)));
                acc[0][c] = __builtin_amdgcn_mfma_f32_16x16x32_bf16(a[mat][0][ks], b, acc[0][c], 0, 0, 0);
                acc[1][c] = __builtin_amdgcn_mfma_f32_16x16x32_bf16(a[mat][1][ks], b, acc[1][c], 0, 0, 0);
            }
        }
    }

    if (m0 + 32 <= M) {
#pragma unroll
        for (int c = 0; c < 8; ++c) {
            int col = c * 16 + l15;
            float bv = bias[col];
#pragma unroll
            for (int rf = 0; rf < 2; ++rf)
#pragma unroll
                for (int j = 0; j < 4; ++j) {
                    int row = m0 + rf * 16 + g * 4 + j;
                    float v = fmaxf(acc[rf][c][j] + bv, 0.f);
                    if (BF16OUT) ((ushort_t*)outv)[(size_t)row * DF + col] = f2bf(v);
                    else         ((float*)outv)[(size_t)row * DF + col] = v;
                }
        }
    } else {
#pragma unroll
        for (int c = 0; c < 8; ++c) {
            int col = c * 16 + l15;
            float bv = bias[col];
#pragma unroll
            for (int rf = 0; rf < 2; ++rf)
#pragma unroll
                for (int j = 0; j < 4; ++j) {
                    int row = m0 + rf * 16 + g * 4 + j;
                    if (row < M) {
                        float v = fmaxf(acc[rf][c][j] + bv, 0.f);
                        if (BF16OUT) ((ushort_t*)outv)[(size_t)row * DF + col] = f2bf(v);
                        else         ((float*)outv)[(size_t)row * DF + col] = v;
                    }
                }
        }
    }
}

extern "C" void kernel_launch(void* const* d_in, const int* in_sizes, int n_in,
                              void* d_out, int out_size, void* d_ws, size_t ws_size,
                              hipStream_t stream) {
    const int N = in_sizes[0] / DF;   // 100000
    const int E = in_sizes[1];        // 1600000

    const float* x   = (const float*)d_in[0];
    const int*   src = (const int*)d_in[1];
    const int*   dst = (const int*)d_in[2];
    const float* Ws1 = (const float*)d_in[3];
    const float* Wn1 = (const float*)d_in[4];
    const float* b1  = (const float*)d_in[5];
    const float* Ws2 = (const float*)d_in[6];
    const float* Wn2 = (const float*)d_in[7];
    const float* b2  = (const float*)d_in[8];
    float* out = (float*)d_out;

    const int NBKT = (N + 255) >> 8;
    int CH = 4096;
    int NCH = (E + CH - 1) / CH;
    while (NCH > 512) { CH <<= 1; NCH = (E + CH - 1) / CH; }

    // workspace layout (~58.7 MB, unchanged)
    int* rowptr   = (int*)d_ws;                                  // N+1
    int* rowbase  = rowptr + ((N + 1 + 63) & ~63);               // NBKT+1
    int* rowtot   = rowbase + ((NBKT + 1 + 63) & ~63);           // NBKT
    int* C        = rowtot + ((NBKT + 63) & ~63);                // NBKT*NCH
    ushort_t* Wt  = (ushort_t*)(C + ((NBKT * NCH + 63) & ~63));  // 4*16384 bf16
    int* edge_src = (int*)(Wt + 65536);                          // E
    ushort_t* Xb  = (ushort_t*)(edge_src + ((E + 63) & ~63));    // N*128 bf16
    ushort_t* Ab  = Xb + (size_t)N * DF;                         // N*128 bf16
    unsigned int* inter = (unsigned int*)Ab;                     // E u32 (dead before Ab use)

    // fp8 gather operands live in d_out (51.2 MB f32; free until gemm2's write).
    // Both are fully rewritten every call before use -> deterministic.
    unsigned char* Xf8  = (unsigned char*)d_out;                 // N*128 fp8 (12.8 MB)
    unsigned char* H1f8 = Xf8 + (size_t)N * DF;                  // N*128 fp8 (12.8 MB)

    conv_dual_kernel<<<(N * DF / 8 + 255) / 256, 256, 0, stream>>>(x, Xb, Xf8, N * DF / 8);
    k1_coarse_hist<<<NCH, 256, 0, stream>>>(dst, C, E, CH, NCH, NBKT);
    k2a_row_scan<<<NBKT, 512, 0, stream>>>(C, rowtot, NCH);
    k2b_base_scan<<<1, 512, 0, stream>>>(rowtot, rowbase, rowptr, NBKT, N, E);
    k3_bin_scatter<<<NCH, 256, 0, stream>>>(src, dst, C, rowbase, inter, E, CH, NCH, NBKT);
    k4_fine_scatter<<<NBKT, 256, 0, stream>>>(inter, rowbase, edge_src, rowptr, N);
    transpose_w_kernel<<<256, 256, 0, stream>>>(Ws1, Wn1, Ws2, Wn2, Wt);

    const int aggGrid  = (N + 3) / 4;
    const int gemmGrid = (N + 127) / 128;

    // layer 1: agg(Xf8) -> Ab ; h1 = relu(Xb@Ws1 + Ab@Wn1 + b1) bf16 in-place over Xb
    aggregate_fp8_kernel<<<aggGrid, 256, 0, stream>>>(Xf8, rowptr, edge_src, Ab, N);
    sage_mfma_kernel<1><<<gemmGrid, 256, 0, stream>>>(Xb, Ab, Wt, Wt + 16384, b1, (void*)Xb, N);
    // h1 -> fp8 for the layer-2 gather
    conv_b2f8_kernel<<<(N * DF / 8 + 255) / 256, 256, 0, stream>>>(Xb, H1f8, N * DF / 8);
    // layer 2: agg(H1f8) -> Ab ; out = relu(h1@Ws2 + Ab@Wn2 + b2) fp32 to d_out
    aggregate_fp8_kernel<<<aggGrid, 256, 0, stream>>>(H1f8, rowptr, edge_src, Ab, N);
    sage_mfma_kernel<0><<<gemmGrid, 256, 0, stream>>>(Xb, Ab, Wt + 32768, Wt + 49152, b2, (void*)out, N);
}